// Round 2
// baseline (5799.797 us; speedup 1.0000x reference)
//
#include <hip/hip_runtime.h>

// ---------------- types & helpers ----------------
typedef float f32x4 __attribute__((ext_vector_type(4)));
typedef __bf16 bf16x8 __attribute__((ext_vector_type(8)));
typedef unsigned short us8 __attribute__((ext_vector_type(8)));

static __device__ __forceinline__ unsigned short f2bf(float f){
    unsigned int u = __builtin_bit_cast(unsigned int, f);
    u += 0x7fffu + ((u >> 16) & 1u);
    return (unsigned short)(u >> 16);
}
static __device__ __forceinline__ float bf2f(unsigned short h){
    unsigned int u = ((unsigned int)h) << 16;
    return __builtin_bit_cast(float, u);
}
static __device__ __forceinline__ bf16x8 ldb8(const unsigned short* p){
    return __builtin_bit_cast(bf16x8, *(const us8*)p);
}
typedef __attribute__((address_space(1))) void gas_void;
typedef __attribute__((address_space(3))) void las_void;
static __device__ __forceinline__ void gload_lds16(const void* g, void* l){
    __builtin_amdgcn_global_load_lds((gas_void*)g, (las_void*)l, 16, 0, 0);
}
static __device__ __forceinline__ float siluf(float v){
    return v / (1.f + __expf(-v));
}

// ---------------- prep: silu(plug_c_ref) rows 0..511, zero rows 512..639 ----------------
__global__ __launch_bounds__(256) void silu_hist_k(const float* __restrict__ plug,
                                                   unsigned short* __restrict__ siluc){
    int i = blockIdx.x*256 + threadIdx.x;
    if (i < 512*1152){
        siluc[i] = f2bf(siluf(plug[i]));
    } else if (i < 640*1152){
        siluc[i] = 0;   // pad rows: safe A-tile overread for M=516 GEMMs
    }
}

// ---------------- prep: timestep MLP -> silu(c_gen) rows 512..515 ----------------
__global__ __launch_bounds__(576) void cgen_k(const float* __restrict__ noise,
    const float* __restrict__ t_w0, const float* __restrict__ t_b0,
    const float* __restrict__ t_w2, const float* __restrict__ t_b2,
    unsigned short* __restrict__ siluc){
    __shared__ float emb[256];
    __shared__ float hl[1152];
    int b = blockIdx.x, t = threadIdx.x;
    float tv = noise[b];
    if (t < 256){
        int j = t & 127;
        float fr = __expf(-0.07195578415606394f * (float)j);
        float arg = tv * fr;
        emb[t] = (t < 128) ? cosf(arg) : sinf(arg);
    }
    __syncthreads();
    for (int c = t; c < 1152; c += 576){
        float s = t_b0[c];
        for (int j = 0; j < 256; j++) s += emb[j] * t_w0[j*1152 + c];
        hl[c] = siluf(s);
    }
    __syncthreads();
    for (int c = t; c < 1152; c += 576){
        float s = t_b2[c];
        for (int j = 0; j < 1152; j++) s += hl[j] * t_w2[j*1152 + c];
        siluc[(size_t)(512 + b)*1152 + c] = f2bf(siluf(s));
    }
}

// ---------------- prep: x0 = tile(concat(rawhist,x),36) + pos_embed ----------------
__global__ __launch_bounds__(256) void x0_k(const float* __restrict__ xg,
    const float* __restrict__ rh, const float* __restrict__ pe, float* __restrict__ x){
    int i4 = blockIdx.x*256 + threadIdx.x;          // float4 index
    if (i4 >= 1179648) return;                      // 4096*1152/4  (was 4x too small!)
    int m = i4 / 288;
    int c = (i4 - m*288) * 4;
    int pos = m & 1023, b = m >> 10;
    const float* src = (pos < 512) ? (rh + ((size_t)b*512 + pos)*32)
                                   : (xg + ((size_t)b*512 + (pos-512))*32);
    float4 sv = *(const float4*)(src + (c & 31));
    float4 pv = *(const float4*)(pe + (size_t)pos*1152 + c);
    float4 o; o.x = sv.x+pv.x; o.y = sv.y+pv.y; o.z = sv.z+pv.z; o.w = sv.w+pv.w;
    *(float4*)(x + (size_t)i4*4) = o;
}

// ---------------- LN (no affine) + modulate -> bf16 ----------------
__global__ __launch_bounds__(256) void ln_mod_k(const float* __restrict__ x,
    const float* __restrict__ modb, int mld, int ofs, unsigned short* __restrict__ y){
    const int m = blockIdx.x, t = threadIdx.x;
    const int lane = t & 63, wv = t >> 6;
    const float* xr = x + (size_t)m*1152;
    float4 v0 = ((const float4*)xr)[t];
    float4 v1 = {0.f,0.f,0.f,0.f};
    bool h2 = (t < 32);
    if (h2) v1 = ((const float4*)xr)[256 + t];
    float s = v0.x+v0.y+v0.z+v0.w + v1.x+v1.y+v1.z+v1.w;
    float q = v0.x*v0.x+v0.y*v0.y+v0.z*v0.z+v0.w*v0.w
            + v1.x*v1.x+v1.y*v1.y+v1.z*v1.z+v1.w*v1.w;
    #pragma unroll
    for (int o = 32; o; o >>= 1){ s += __shfl_xor(s,o); q += __shfl_xor(q,o); }
    __shared__ float red[8];
    if (lane == 0){ red[wv] = s; red[4+wv] = q; }
    __syncthreads();
    s = red[0]+red[1]+red[2]+red[3];
    q = red[4]+red[5]+red[6]+red[7];
    const float mean = s * (1.f/1152.f);
    const float var  = q * (1.f/1152.f) - mean*mean;
    const float rstd = rsqrtf(var + 1e-6f);
    const int pos = m & 1023, bb = m >> 10;
    const int mrow = (pos < 512) ? pos : (512 + bb);
    const float* sh = modb + (size_t)mrow*mld + ofs;
    const float* sc = sh + 1152;
    {
        int c = t*4;
        float4 shv = *(const float4*)(sh + c);
        float4 scv = *(const float4*)(sc + c);
        ushort4 o4;
        o4.x = f2bf((v0.x-mean)*rstd*(1.f+scv.x) + shv.x);
        o4.y = f2bf((v0.y-mean)*rstd*(1.f+scv.y) + shv.y);
        o4.z = f2bf((v0.z-mean)*rstd*(1.f+scv.z) + shv.z);
        o4.w = f2bf((v0.w-mean)*rstd*(1.f+scv.w) + shv.w);
        *(ushort4*)(y + (size_t)m*1152 + c) = o4;
    }
    if (h2){
        int c = 1024 + t*4;
        float4 shv = *(const float4*)(sh + c);
        float4 scv = *(const float4*)(sc + c);
        ushort4 o4;
        o4.x = f2bf((v1.x-mean)*rstd*(1.f+scv.x) + shv.x);
        o4.y = f2bf((v1.y-mean)*rstd*(1.f+scv.y) + shv.y);
        o4.z = f2bf((v1.z-mean)*rstd*(1.f+scv.z) + shv.z);
        o4.w = f2bf((v1.w-mean)*rstd*(1.f+scv.w) + shv.w);
        *(ushort4*)(y + (size_t)m*1152 + c) = o4;
    }
}

// ---------------- GEMM: out = epi(A(bf16, MxK) @ W(f32, KxN) + bias) ----------------
// EPI: 0 = bf16 store, 1 = gelu->bf16, 2 = f32 store (guard row<M), 3 = x += gate*(v)
template<int EPI>
__global__ __launch_bounds__(256,2)
void gemm_k(const unsigned short* __restrict__ A, int lda,
            const float* __restrict__ W, int ldw,
            const float* __restrict__ bias,
            unsigned short* __restrict__ outb,
            float* __restrict__ outf,
            int M, int K,
            float* __restrict__ xres,
            const float* __restrict__ modb, int mld, int gofs){
    __shared__ unsigned short Alds[128*32];
    __shared__ unsigned short Wlds[128*40];   // transposed W tile, padded pitch 40 (=80B, 16B-mult)
    const int tid  = threadIdx.x;
    const int lane = tid & 63;
    const int wv   = tid >> 6;
    const int wr   = wv >> 1, wc = wv & 1;
    const int m0 = blockIdx.x * 128;          // M fastest -> same-W-panel blocks cluster
    const int n0 = blockIdx.y * 128;

    // A staging: 2x 16B chunks per lane via global_load_lds
    const int arow0 = (wv*2 + 0)*16 + (lane >> 2);
    const int arow1 = (wv*2 + 1)*16 + (lane >> 2);
    const unsigned short* ag0 = A + (size_t)(m0 + arow0)*lda + (lane & 3)*8;
    const unsigned short* ag1 = A + (size_t)(m0 + arow1)*lda + (lane & 3)*8;
    unsigned short* al0 = &Alds[(wv*2 + 0)*512];
    unsigned short* al1 = &Alds[(wv*2 + 1)*512];

    // W staging: 4k x 4n per thread, transpose-convert into Wlds[n][k]
    const int kq = (tid >> 5) * 4;            // 0..28
    const int nb = (tid & 31) * 4;            // 0..124
    const float* wg = W + (size_t)kq*ldw + n0 + nb;

    f32x4 acc[4][4];
    #pragma unroll
    for (int i = 0; i < 4; i++)
        #pragma unroll
        for (int j = 0; j < 4; j++){ f32x4 z = {0.f,0.f,0.f,0.f}; acc[i][j] = z; }

    for (int ks = 0; ks < K; ks += 32){
        if (ks) __syncthreads();
        float4 r0 = *(const float4*)(wg + (size_t)0*ldw);
        float4 r1 = *(const float4*)(wg + (size_t)1*ldw);
        float4 r2 = *(const float4*)(wg + (size_t)2*ldw);
        float4 r3 = *(const float4*)(wg + (size_t)3*ldw);
        wg += (size_t)32*ldw;
        gload_lds16((const void*)ag0, (void*)al0);
        gload_lds16((const void*)ag1, (void*)al1);
        ag0 += 32; ag1 += 32;
        {
            ushort4 p;
            p.x=f2bf(r0.x); p.y=f2bf(r1.x); p.z=f2bf(r2.x); p.w=f2bf(r3.x);
            *(ushort4*)&Wlds[(nb+0)*40 + kq] = p;
            p.x=f2bf(r0.y); p.y=f2bf(r1.y); p.z=f2bf(r2.y); p.w=f2bf(r3.y);
            *(ushort4*)&Wlds[(nb+1)*40 + kq] = p;
            p.x=f2bf(r0.z); p.y=f2bf(r1.z); p.z=f2bf(r2.z); p.w=f2bf(r3.z);
            *(ushort4*)&Wlds[(nb+2)*40 + kq] = p;
            p.x=f2bf(r0.w); p.y=f2bf(r1.w); p.z=f2bf(r2.w); p.w=f2bf(r3.w);
            *(ushort4*)&Wlds[(nb+3)*40 + kq] = p;
        }
        __syncthreads();
        bf16x8 af[4], bfm[4];
        #pragma unroll
        for (int mt = 0; mt < 4; mt++)
            af[mt] = ldb8(&Alds[(wr*64 + mt*16 + (lane&15))*32 + (lane>>4)*8]);
        #pragma unroll
        for (int nt = 0; nt < 4; nt++)
            bfm[nt] = ldb8(&Wlds[(wc*64 + nt*16 + (lane&15))*40 + (lane>>4)*8]);
        #pragma unroll
        for (int mt = 0; mt < 4; mt++)
            #pragma unroll
            for (int nt = 0; nt < 4; nt++)
                acc[mt][nt] = __builtin_amdgcn_mfma_f32_16x16x32_bf16(af[mt], bfm[nt], acc[mt][nt], 0,0,0);
    }

    const int cb = n0 + wc*64;
    const int rb = m0 + wr*64;
    #pragma unroll
    for (int nt = 0; nt < 4; nt++){
        int col = cb + nt*16 + (lane & 15);
        float bn = bias[col];
        #pragma unroll
        for (int mt = 0; mt < 4; mt++){
            #pragma unroll
            for (int i = 0; i < 4; i++){
                int row = rb + mt*16 + (lane>>4)*4 + i;
                float v = acc[mt][nt][i] + bn;
                if (EPI == 0){
                    outb[(size_t)row*ldw + col] = f2bf(v);
                } else if (EPI == 1){
                    float z = 0.7978845608f*(v + 0.044715f*v*v*v);
                    float e = __expf(-2.f*fabsf(z));
                    float th = (1.f - e)/(1.f + e);
                    th = (z >= 0.f) ? th : -th;
                    outb[(size_t)row*ldw + col] = f2bf(0.5f*v*(1.f + th));
                } else if (EPI == 2){
                    if (row < M) outf[(size_t)row*ldw + col] = v;
                } else {
                    int pos = row & 1023, bb2 = row >> 10;
                    int mrow = (pos < 512) ? pos : (512 + bb2);
                    float g = modb[(size_t)mrow*mld + gofs + col];
                    xres[(size_t)row*1152 + col] += g * v;
                }
            }
        }
    }
}

// ---------------- flash attention (causal), 1 wave = 16 q rows ----------------
__global__ __launch_bounds__(128)
void attn_k(const unsigned short* __restrict__ qkv, unsigned short* __restrict__ o){
    __shared__ unsigned short Qs[2][16*96];
    __shared__ unsigned short Ks[2][32*96];
    __shared__ unsigned short Vs[2][32*96];
    __shared__ unsigned short Ps[2][16*32];
    const int w = threadIdx.x >> 6;
    const int lane = threadIdx.x & 63;
    const int idx = blockIdx.x*2 + w;
    const int qt = idx & 63;
    const int bh = idx >> 6;
    const int h = bh & 15, b = bh >> 4;
    unsigned short* Q  = Qs[w];
    unsigned short* Kl = Ks[w];
    unsigned short* Vl = Vs[w];
    unsigned short* Pl = Ps[w];

    {   // zero Q/K/V (pads must be 0)
        us8 z = {0,0,0,0,0,0,0,0};
        for (int i = lane; i < 192; i += 64) *(us8*)&Q[i*8] = z;
        for (int i = lane; i < 384; i += 64){ *(us8*)&Kl[i*8] = z; *(us8*)&Vl[i*8] = z; }
    }
    const size_t base = (size_t)b*1024*3456;
    const int qcol = h*72, kcol = 1152 + h*72, vcol = 2304 + h*72;
    // Q load: 8B chunks (16B chunks would be misaligned for odd heads: h*144 B)
    for (int ch = lane; ch < 288; ch += 64){
        int row = ch/18, d4 = (ch - row*18)*4;
        *(ushort4*)&Q[row*96 + d4] = *(const ushort4*)(qkv + base + (size_t)(qt*16+row)*3456 + qcol + d4);
    }
    float mi[4], li[4];
    f32x4 oa[5];
    #pragma unroll
    for (int i = 0; i < 4; i++){ mi[i] = -INFINITY; li[i] = 0.f; }
    #pragma unroll
    for (int d = 0; d < 5; d++){ f32x4 z = {0.f,0.f,0.f,0.f}; oa[d] = z; }

    const int nkv = (qt >> 1) + 1;
    const float qsc = 0.11785113019775793f;   // 72^-0.5
    for (int kt = 0; kt < nkv; kt++){
        int kvb = kt*32;
        for (int ch = lane; ch < 576; ch += 64){
            int row = ch/18, d4 = (ch - row*18)*4;
            size_t g = base + (size_t)(kvb+row)*3456 + d4;
            *(ushort4*)&Kl[row*96 + d4] = *(const ushort4*)(qkv + g + kcol);
            *(ushort4*)&Vl[row*96 + d4] = *(const ushort4*)(qkv + g + vcol);
        }
        f32x4 s0 = {0.f,0.f,0.f,0.f}, s1 = {0.f,0.f,0.f,0.f};
        #pragma unroll
        for (int st = 0; st < 3; st++){
            bf16x8 aq = ldb8(&Q [(lane&15)*96 + (lane>>4)*8 + st*32]);
            bf16x8 k0 = ldb8(&Kl[(lane&15)*96 + (lane>>4)*8 + st*32]);
            bf16x8 k1 = ldb8(&Kl[(16+(lane&15))*96 + (lane>>4)*8 + st*32]);
            s0 = __builtin_amdgcn_mfma_f32_16x16x32_bf16(aq, k0, s0, 0,0,0);
            s1 = __builtin_amdgcn_mfma_f32_16x16x32_bf16(aq, k1, s1, 0,0,0);
        }
        bool mlast = (kt == nkv-1);
        float p0[4], p1[4];
        #pragma unroll
        for (int i = 0; i < 4; i++){
            float a = s0[i]*qsc, c = s1[i]*qsc;
            if (mlast){
                int r = qt*16 + (lane>>4)*4 + i;
                if (kvb + (lane&15) > r) a = -1e30f;
                if (kvb + 16 + (lane&15) > r) c = -1e30f;
            }
            float pm = fmaxf(a, c);
            #pragma unroll
            for (int off = 1; off < 16; off <<= 1) pm = fmaxf(pm, __shfl_xor(pm, off));
            float nm = fmaxf(mi[i], pm);
            float f = __expf(mi[i] - nm);
            mi[i] = nm;
            a = __expf(a - nm); c = __expf(c - nm);
            float rs = a + c;
            #pragma unroll
            for (int off = 1; off < 16; off <<= 1) rs += __shfl_xor(rs, off);
            li[i] = li[i]*f + rs;
            #pragma unroll
            for (int d = 0; d < 5; d++) oa[d][i] *= f;
            p0[i] = a; p1[i] = c;
        }
        #pragma unroll
        for (int i = 0; i < 4; i++){
            int r = (lane>>4)*4 + i;
            Pl[r*32 + (lane&15)]      = f2bf(p0[i]);
            Pl[r*32 + 16 + (lane&15)] = f2bf(p1[i]);
        }
        bf16x8 pa = ldb8(&Pl[(lane&15)*32 + (lane>>4)*8]);
        #pragma unroll
        for (int d = 0; d < 5; d++){
            us8 bv;
            #pragma unroll
            for (int i8 = 0; i8 < 8; i8++)
                bv[i8] = Vl[((lane>>4)*8 + i8)*96 + d*16 + (lane&15)];
            oa[d] = __builtin_amdgcn_mfma_f32_16x16x32_bf16(pa, __builtin_bit_cast(bf16x8, bv), oa[d], 0,0,0);
        }
    }
    #pragma unroll
    for (int i = 0; i < 4; i++){
        float inv = 1.f / li[i];
        size_t row = (size_t)b*1024 + qt*16 + (lane>>4)*4 + i;
        #pragma unroll
        for (int d = 0; d < 5; d++){
            int c = d*16 + (lane & 15);
            if (c < 72) o[row*1152 + h*72 + c] = f2bf(oa[d][i]*inv);
        }
    }
}

// ---------------- final: out = modulate(x, sh, sc) @ fin_w + fin_b (GEN rows) ----------------
__global__ __launch_bounds__(256) void final_k(const float* __restrict__ x,
    const float* __restrict__ modf, const float* __restrict__ finw,
    const float* __restrict__ finb, float* __restrict__ outp){
    __shared__ float yl[1152];
    __shared__ float ps[8][32];
    const int t = threadIdx.x;
    for (int r = 0; r < 8; r++){
        int gr = blockIdx.x*8 + r;              // 0..2047 GEN rows
        int b = gr >> 9, p = gr & 511;
        size_t m = (size_t)b*1024 + 512 + p;
        int mrow = 512 + b;
        const float* xr = x + m*1152;
        const float* md = modf + (size_t)mrow*2304;
        for (int c = t; c < 1152; c += 256)
            yl[c] = xr[c]*(1.f + md[1152 + c]) + md[c];
        __syncthreads();
        int j = t & 31, g = t >> 5;
        float s = 0.f;
        for (int c = g*144; c < g*144 + 144; c++) s += yl[c]*finw[c*32 + j];
        ps[g][j] = s;
        __syncthreads();
        if (t < 32){
            float acc = finb[j];
            #pragma unroll
            for (int gg = 0; gg < 8; gg++) acc += ps[gg][j];
            outp[((size_t)b*512 + p)*32 + j] = acc;
        }
        __syncthreads();
    }
}

// ---------------- host launch ----------------
extern "C" void kernel_launch(void* const* d_in, const int* in_sizes, int n_in,
                              void* d_out, int out_size, void* d_ws, size_t ws_size,
                              hipStream_t stream){
    const float* xin   = (const float*)d_in[0];
    const float* noise = (const float*)d_in[1];
    const float* rawh  = (const float*)d_in[2];
    const float* pose  = (const float*)d_in[4];
    const float* plug  = (const float*)d_in[5];
    const float* t_w0  = (const float*)d_in[6];
    const float* t_b0  = (const float*)d_in[7];
    const float* t_w2  = (const float*)d_in[8];
    const float* t_b2  = (const float*)d_in[9];
    const float* qkvw  = (const float*)d_in[10];
    const float* qkvb  = (const float*)d_in[11];
    const float* projw = (const float*)d_in[12];
    const float* projb = (const float*)d_in[13];
    const float* fc1w  = (const float*)d_in[14];
    const float* fc1b  = (const float*)d_in[15];
    const float* fc2w  = (const float*)d_in[16];
    const float* fc2b  = (const float*)d_in[17];
    const float* adaw  = (const float*)d_in[18];
    const float* adab  = (const float*)d_in[19];
    const float* finaw = (const float*)d_in[20];
    const float* finab = (const float*)d_in[21];
    const float* finw  = (const float*)d_in[22];
    const float* finb  = (const float*)d_in[23];

    char* ws = (char*)d_ws;
    float*          xbuf  = (float*)(ws + 0);                      // 4096x1152 f32
    unsigned short* ybuf  = (unsigned short*)(ws + 18874368);      // 4096x1152 bf16
    unsigned short* qh    = (unsigned short*)(ws + 28311552);      // 4096x4608 bf16 (qkv/h)
    unsigned short* obuf  = (unsigned short*)(ws + 66060288);      // 4096x1152 bf16
    unsigned short* siluc = (unsigned short*)(ws + 75497472);      // 640x1152 bf16
    float*          modb  = (float*)(ws + 76972032);               // 640x6912 f32

    silu_hist_k<<<2880,256,0,stream>>>(plug, siluc);
    cgen_k<<<4,576,0,stream>>>(noise, t_w0, t_b0, t_w2, t_b2, siluc);
    x0_k<<<4608,256,0,stream>>>(xin, rawh, pose, xbuf);

    for (int l = 0; l < 7; l++){
        gemm_k<2><<<dim3(5,54),256,0,stream>>>(siluc,1152, adaw + (size_t)l*1152*6912, 6912,
            adab + (size_t)l*6912, nullptr, modb, 516, 1152, nullptr, nullptr, 0, 0);
        ln_mod_k<<<4096,256,0,stream>>>(xbuf, modb, 6912, 0, ybuf);
        gemm_k<0><<<dim3(32,27),256,0,stream>>>(ybuf,1152, qkvw + (size_t)l*1152*3456, 3456,
            qkvb + (size_t)l*3456, qh, nullptr, 4096, 1152, nullptr, nullptr, 0, 0);
        attn_k<<<2048,128,0,stream>>>(qh, obuf);
        gemm_k<3><<<dim3(32,9),256,0,stream>>>(obuf,1152, projw + (size_t)l*1152*1152, 1152,
            projb + (size_t)l*1152, nullptr, nullptr, 4096, 1152, xbuf, modb, 6912, 2304);
        ln_mod_k<<<4096,256,0,stream>>>(xbuf, modb, 6912, 3456, ybuf);
        gemm_k<1><<<dim3(32,36),256,0,stream>>>(ybuf,1152, fc1w + (size_t)l*1152*4608, 4608,
            fc1b + (size_t)l*4608, qh, nullptr, 4096, 1152, nullptr, nullptr, 0, 0);
        gemm_k<3><<<dim3(32,9),256,0,stream>>>(qh,4608, fc2w + (size_t)l*4608*1152, 1152,
            fc2b + (size_t)l*1152, nullptr, nullptr, 4096, 4608, xbuf, modb, 6912, 5760);
    }
    gemm_k<2><<<dim3(5,18),256,0,stream>>>(siluc,1152, finaw, 2304, finab,
        nullptr, modb, 516, 1152, nullptr, nullptr, 0, 0);
    final_k<<<256,256,0,stream>>>(xbuf, modb, finw, finb, (float*)d_out);
}

// Round 3
// 3583.304 us; speedup vs baseline: 1.6186x; 1.6186x over previous
//
#include <hip/hip_runtime.h>

// ---------------- types & helpers ----------------
typedef float f32x4 __attribute__((ext_vector_type(4)));
typedef __bf16 bf16x8 __attribute__((ext_vector_type(8)));
typedef unsigned short us8 __attribute__((ext_vector_type(8)));

static __device__ __forceinline__ unsigned short f2bf(float f){
    unsigned int u = __builtin_bit_cast(unsigned int, f);
    u += 0x7fffu + ((u >> 16) & 1u);
    return (unsigned short)(u >> 16);
}
static __device__ __forceinline__ bf16x8 ldb8(const unsigned short* p){
    return __builtin_bit_cast(bf16x8, *(const us8*)p);
}
typedef __attribute__((address_space(1))) void gas_void;
typedef __attribute__((address_space(3))) void las_void;
static __device__ __forceinline__ void gload_lds16(const void* g, void* l){
    __builtin_amdgcn_global_load_lds((gas_void*)g, (las_void*)l, 16, 0, 0);
}
static __device__ __forceinline__ float siluf(float v){
    return v / (1.f + __expf(-v));
}

// ---------------- prep: silu(plug_c_ref) rows 0..511, zero pad rows 512..639 ----------------
__global__ __launch_bounds__(256) void silu_hist_k(const float* __restrict__ plug,
                                                   unsigned short* __restrict__ siluc){
    int i = blockIdx.x*256 + threadIdx.x;
    if (i < 512*1152){
        siluc[i] = f2bf(siluf(plug[i]));
    } else if (i < 640*1152){
        siluc[i] = 0;   // pad rows: safe A-tile overread for M=516 GEMMs
    }
}

// ---------------- prep: timestep MLP -> silu(c_gen) rows 512..515 ----------------
__global__ __launch_bounds__(576) void cgen_k(const float* __restrict__ noise,
    const float* __restrict__ t_w0, const float* __restrict__ t_b0,
    const float* __restrict__ t_w2, const float* __restrict__ t_b2,
    unsigned short* __restrict__ siluc){
    __shared__ float emb[256];
    __shared__ float hl[1152];
    int b = blockIdx.x, t = threadIdx.x;
    float tv = noise[b];
    if (t < 256){
        int j = t & 127;
        float fr = __expf(-0.07195578415606394f * (float)j);
        float arg = tv * fr;
        emb[t] = (t < 128) ? cosf(arg) : sinf(arg);
    }
    __syncthreads();
    for (int c = t; c < 1152; c += 576){
        float s = t_b0[c];
        for (int j = 0; j < 256; j++) s += emb[j] * t_w0[j*1152 + c];
        hl[c] = siluf(s);
    }
    __syncthreads();
    for (int c = t; c < 1152; c += 576){
        float s = t_b2[c];
        for (int j = 0; j < 1152; j++) s += hl[j] * t_w2[j*1152 + c];
        siluc[(size_t)(512 + b)*1152 + c] = f2bf(siluf(s));
    }
}

// ---------------- prep: x0 = tile(concat(rawhist,x),36) + pos_embed ----------------
__global__ __launch_bounds__(256) void x0_k(const float* __restrict__ xg,
    const float* __restrict__ rh, const float* __restrict__ pe, float* __restrict__ x){
    int i4 = blockIdx.x*256 + threadIdx.x;          // float4 index
    if (i4 >= 1179648) return;                      // 4096*1152/4
    int m = i4 / 288;
    int c = (i4 - m*288) * 4;
    int pos = m & 1023, b = m >> 10;
    const float* src = (pos < 512) ? (rh + ((size_t)b*512 + pos)*32)
                                   : (xg + ((size_t)b*512 + (pos-512))*32);
    float4 sv = *(const float4*)(src + (c & 31));
    float4 pv = *(const float4*)(pe + (size_t)pos*1152 + c);
    float4 o; o.x = sv.x+pv.x; o.y = sv.y+pv.y; o.z = sv.z+pv.z; o.w = sv.w+pv.w;
    *(float4*)(x + (size_t)i4*4) = o;
}

// ---------------- weight transpose-convert: W f32 [K][N] -> Wt bf16 [N][K] ----------------
__global__ __launch_bounds__(256) void tw_k(const float* __restrict__ W, int Kd, int Nd,
                                            unsigned short* __restrict__ Wt){
    __shared__ float tile[32][33];
    int n0 = blockIdx.x*32, k0 = blockIdx.y*32;
    int t = threadIdx.x;
    #pragma unroll
    for (int i = 0; i < 4; i++){
        int idx = t + 256*i;
        int kk = idx >> 5, nn = idx & 31;
        tile[kk][nn] = W[(size_t)(k0+kk)*Nd + n0+nn];
    }
    __syncthreads();
    #pragma unroll
    for (int i = 0; i < 4; i++){
        int idx = t + 256*i;
        int nn = idx >> 5, kk = idx & 31;
        Wt[(size_t)(n0+nn)*Kd + k0+kk] = f2bf(tile[kk][nn]);
    }
}

// ---------------- LN (no affine) + modulate -> bf16 ----------------
__global__ __launch_bounds__(256) void ln_mod_k(const float* __restrict__ x,
    const float* __restrict__ modb, int mld, int ofs, unsigned short* __restrict__ y){
    const int m = blockIdx.x, t = threadIdx.x;
    const int lane = t & 63, wv = t >> 6;
    const float* xr = x + (size_t)m*1152;
    float4 v0 = ((const float4*)xr)[t];
    float4 v1 = {0.f,0.f,0.f,0.f};
    bool h2 = (t < 32);
    if (h2) v1 = ((const float4*)xr)[256 + t];
    float s = v0.x+v0.y+v0.z+v0.w + v1.x+v1.y+v1.z+v1.w;
    float q = v0.x*v0.x+v0.y*v0.y+v0.z*v0.z+v0.w*v0.w
            + v1.x*v1.x+v1.y*v1.y+v1.z*v1.z+v1.w*v1.w;
    #pragma unroll
    for (int o = 32; o; o >>= 1){ s += __shfl_xor(s,o); q += __shfl_xor(q,o); }
    __shared__ float red[8];
    if (lane == 0){ red[wv] = s; red[4+wv] = q; }
    __syncthreads();
    s = red[0]+red[1]+red[2]+red[3];
    q = red[4]+red[5]+red[6]+red[7];
    const float mean = s * (1.f/1152.f);
    const float var  = q * (1.f/1152.f) - mean*mean;
    const float rstd = rsqrtf(var + 1e-6f);
    const int pos = m & 1023, bb = m >> 10;
    const int mrow = (pos < 512) ? pos : (512 + bb);
    const float* sh = modb + (size_t)mrow*mld + ofs;
    const float* sc = sh + 1152;
    {
        int c = t*4;
        float4 shv = *(const float4*)(sh + c);
        float4 scv = *(const float4*)(sc + c);
        ushort4 o4;
        o4.x = f2bf((v0.x-mean)*rstd*(1.f+scv.x) + shv.x);
        o4.y = f2bf((v0.y-mean)*rstd*(1.f+scv.y) + shv.y);
        o4.z = f2bf((v0.z-mean)*rstd*(1.f+scv.z) + shv.z);
        o4.w = f2bf((v0.w-mean)*rstd*(1.f+scv.w) + shv.w);
        *(ushort4*)(y + (size_t)m*1152 + c) = o4;
    }
    if (h2){
        int c = 1024 + t*4;
        float4 shv = *(const float4*)(sh + c);
        float4 scv = *(const float4*)(sc + c);
        ushort4 o4;
        o4.x = f2bf((v1.x-mean)*rstd*(1.f+scv.x) + shv.x);
        o4.y = f2bf((v1.y-mean)*rstd*(1.f+scv.y) + shv.y);
        o4.z = f2bf((v1.z-mean)*rstd*(1.f+scv.z) + shv.z);
        o4.w = f2bf((v1.w-mean)*rstd*(1.f+scv.w) + shv.w);
        *(ushort4*)(y + (size_t)m*1152 + c) = o4;
    }
}

// ---------------- GEMM (m97 structure): out = epi(A(bf16,MxK) @ Wt^T + bias) ----------------
// A row-major [M][K] lda; B = Wt row-major [N][K] ldb. Both staged via global_load_lds.
// EPI: 0 = bf16 store, 1 = gelu->bf16, 2 = f32 store (guard row<M), 3 = x += gate*(v)
template<int EPI>
__global__ __launch_bounds__(256,2)
void gemm2_k(const unsigned short* __restrict__ A, int lda,
             const unsigned short* __restrict__ B, int ldb,
             const float* __restrict__ bias,
             unsigned short* __restrict__ outb, float* __restrict__ outf, int ldo,
             int M, int K,
             float* __restrict__ xres,
             const float* __restrict__ modb, int mld, int gofs){
    __shared__ unsigned short Alds[128*32];
    __shared__ unsigned short Blds[128*32];
    const int tid  = threadIdx.x;
    const int lane = tid & 63;
    const int wv   = tid >> 6;
    const int wr   = wv >> 1, wc = wv & 1;
    const int m0 = blockIdx.x * 128;          // M fastest -> same-W-panel blocks cluster
    const int n0 = blockIdx.y * 128;

    const int r0 = (wv*2 + 0)*16 + (lane >> 2);
    const int r1 = (wv*2 + 1)*16 + (lane >> 2);
    const unsigned short* ag0 = A + (size_t)(m0 + r0)*lda + (lane & 3)*8;
    const unsigned short* ag1 = A + (size_t)(m0 + r1)*lda + (lane & 3)*8;
    const unsigned short* bg0 = B + (size_t)(n0 + r0)*ldb + (lane & 3)*8;
    const unsigned short* bg1 = B + (size_t)(n0 + r1)*ldb + (lane & 3)*8;
    unsigned short* al0 = &Alds[(wv*2 + 0)*512];
    unsigned short* al1 = &Alds[(wv*2 + 1)*512];
    unsigned short* bl0 = &Blds[(wv*2 + 0)*512];
    unsigned short* bl1 = &Blds[(wv*2 + 1)*512];

    f32x4 acc[4][4];
    #pragma unroll
    for (int i = 0; i < 4; i++)
        #pragma unroll
        for (int j = 0; j < 4; j++){ f32x4 z = {0.f,0.f,0.f,0.f}; acc[i][j] = z; }

    for (int ks = 0; ks < K; ks += 32){
        if (ks) __syncthreads();
        gload_lds16((const void*)ag0, (void*)al0);
        gload_lds16((const void*)ag1, (void*)al1);
        gload_lds16((const void*)bg0, (void*)bl0);
        gload_lds16((const void*)bg1, (void*)bl1);
        ag0 += 32; ag1 += 32; bg0 += 32; bg1 += 32;
        __syncthreads();
        bf16x8 af[4], bfm[4];
        #pragma unroll
        for (int mt = 0; mt < 4; mt++)
            af[mt] = ldb8(&Alds[(wr*64 + mt*16 + (lane&15))*32 + (lane>>4)*8]);
        #pragma unroll
        for (int nt = 0; nt < 4; nt++)
            bfm[nt] = ldb8(&Blds[(wc*64 + nt*16 + (lane&15))*32 + (lane>>4)*8]);
        #pragma unroll
        for (int mt = 0; mt < 4; mt++)
            #pragma unroll
            for (int nt = 0; nt < 4; nt++)
                acc[mt][nt] = __builtin_amdgcn_mfma_f32_16x16x32_bf16(af[mt], bfm[nt], acc[mt][nt], 0,0,0);
    }

    const int cb = n0 + wc*64;
    const int rb = m0 + wr*64;
    #pragma unroll
    for (int nt = 0; nt < 4; nt++){
        int col = cb + nt*16 + (lane & 15);
        float bn = bias[col];
        #pragma unroll
        for (int mt = 0; mt < 4; mt++){
            #pragma unroll
            for (int i = 0; i < 4; i++){
                int row = rb + mt*16 + (lane>>4)*4 + i;
                float v = acc[mt][nt][i] + bn;
                if (EPI == 0){
                    outb[(size_t)row*ldo + col] = f2bf(v);
                } else if (EPI == 1){
                    float z = 0.7978845608f*(v + 0.044715f*v*v*v);
                    float e = __expf(-2.f*fabsf(z));
                    float th = (1.f - e)/(1.f + e);
                    th = (z >= 0.f) ? th : -th;
                    outb[(size_t)row*ldo + col] = f2bf(0.5f*v*(1.f + th));
                } else if (EPI == 2){
                    if (row < M) outf[(size_t)row*ldo + col] = v;
                } else {
                    int pos = row & 1023, bb2 = row >> 10;
                    int mrow = (pos < 512) ? pos : (512 + bb2);
                    float g = modb[(size_t)mrow*mld + gofs + col];
                    xres[(size_t)row*1152 + col] += g * v;
                }
            }
        }
    }
}

// ---------------- flash attention v2: 4 waves/block, 64 q rows, shared K + transposed V ----------------
__global__ __launch_bounds__(256)
void attn2_k(const unsigned short* __restrict__ qkv, unsigned short* __restrict__ o){
    __shared__ unsigned short Q[64*104];      // padded pitch 104 (52 words)
    __shared__ unsigned short Kl[32*104];
    __shared__ unsigned short Vt[96*40];      // V transposed [d][kv], pitch 40 (20 words)
    __shared__ unsigned short Pl[4][16*40];   // per-wave P, pitch 40
    const int tid  = threadIdx.x;
    const int lane = tid & 63;
    const int w    = tid >> 6;
    const int qb = blockIdx.x & 15;
    const int bh = blockIdx.x >> 4;
    const int h = bh & 15, b = bh >> 4;
    const size_t base = (size_t)b*1024*3456;
    const int qcol = h*72, kcol = 1152 + h*72, vcol = 2304 + h*72;

    {   // zero pads once: Q cols 72..103, K cols 72..103, Vt rows 72..95
        ushort4 z4 = {0,0,0,0};
        for (int i = tid; i < 512; i += 256){ int r = i>>3, j = i&7; *(ushort4*)&Q[r*104 + 72 + j*4] = z4; }
        { int i = tid; if (i < 256){ int r = i>>3, j = i&7; *(ushort4*)&Kl[r*104 + 72 + j*4] = z4; } }
        { int i = tid; if (i < 240){ int r = 72 + i/10, j = i - (i/10)*10; *(ushort4*)&Vt[r*40 + j*4] = z4; } }
    }
    // Q: 64 rows x 72 cols, ushort4 chunks
    for (int ch = tid; ch < 1152; ch += 256){
        int r = ch/18, d4 = (ch - r*18)*4;
        *(ushort4*)&Q[r*104 + d4] = *(const ushort4*)(qkv + base + (size_t)(qb*64 + r)*3456 + qcol + d4);
    }

    float mi[4], li[4];
    f32x4 oa[5];
    #pragma unroll
    for (int i = 0; i < 4; i++){ mi[i] = -INFINITY; li[i] = 0.f; }
    #pragma unroll
    for (int d = 0; d < 5; d++){ f32x4 z = {0.f,0.f,0.f,0.f}; oa[d] = z; }

    const int q0 = qb*64 + w*16;              // this wave's first q row (absolute)
    const int ktmax = 2*qb + 2;
    const float qsc = 0.11785113019775793f;   // 72^-0.5

    for (int kt = 0; kt < ktmax; kt++){
        const int kvb = kt*32;
        __syncthreads();
        for (int ch = tid; ch < 576; ch += 256){
            int r = ch/18, d4 = (ch - r*18)*4;
            size_t g = base + (size_t)(kvb + r)*3456 + d4;
            *(ushort4*)&Kl[r*104 + d4] = *(const ushort4*)(qkv + g + kcol);
            ushort4 vv = *(const ushort4*)(qkv + g + vcol);
            Vt[(d4+0)*40 + r] = vv.x;
            Vt[(d4+1)*40 + r] = vv.y;
            Vt[(d4+2)*40 + r] = vv.z;
            Vt[(d4+3)*40 + r] = vv.w;
        }
        __syncthreads();
        if (kvb > q0 + 15) continue;          // wave-uniform skip (no barriers inside)

        f32x4 s0 = {0.f,0.f,0.f,0.f}, s1 = {0.f,0.f,0.f,0.f};
        const unsigned short* Qw = &Q[(w*16)*104];
        #pragma unroll
        for (int st = 0; st < 3; st++){
            bf16x8 aq = ldb8(&Qw[(lane&15)*104 + (lane>>4)*8 + st*32]);
            bf16x8 k0 = ldb8(&Kl[(lane&15)*104 + (lane>>4)*8 + st*32]);
            bf16x8 k1 = ldb8(&Kl[(16+(lane&15))*104 + (lane>>4)*8 + st*32]);
            s0 = __builtin_amdgcn_mfma_f32_16x16x32_bf16(aq, k0, s0, 0,0,0);
            s1 = __builtin_amdgcn_mfma_f32_16x16x32_bf16(aq, k1, s1, 0,0,0);
        }
        const bool domask = (kvb + 31 > q0);
        float p0[4], p1[4];
        #pragma unroll
        for (int i = 0; i < 4; i++){
            float a = s0[i]*qsc, c = s1[i]*qsc;
            if (domask){
                int r = q0 + (lane>>4)*4 + i;
                if (kvb + (lane&15) > r) a = -1e30f;
                if (kvb + 16 + (lane&15) > r) c = -1e30f;
            }
            float pm = fmaxf(a, c);
            #pragma unroll
            for (int off = 1; off < 16; off <<= 1) pm = fmaxf(pm, __shfl_xor(pm, off));
            float nm = fmaxf(mi[i], pm);
            float f = __expf(mi[i] - nm);
            mi[i] = nm;
            a = __expf(a - nm); c = __expf(c - nm);
            float rs = a + c;
            #pragma unroll
            for (int off = 1; off < 16; off <<= 1) rs += __shfl_xor(rs, off);
            li[i] = li[i]*f + rs;
            #pragma unroll
            for (int d = 0; d < 5; d++) oa[d][i] *= f;
            p0[i] = a; p1[i] = c;
        }
        unsigned short* Pw = Pl[w];
        #pragma unroll
        for (int i = 0; i < 4; i++){
            int r = (lane>>4)*4 + i;
            Pw[r*40 + (lane&15)]      = f2bf(p0[i]);
            Pw[r*40 + 16 + (lane&15)] = f2bf(p1[i]);
        }
        bf16x8 pa = ldb8(&Pw[(lane&15)*40 + (lane>>4)*8]);
        #pragma unroll
        for (int d = 0; d < 5; d++){
            bf16x8 bv = ldb8(&Vt[(d*16 + (lane&15))*40 + (lane>>4)*8]);
            oa[d] = __builtin_amdgcn_mfma_f32_16x16x32_bf16(pa, bv, oa[d], 0,0,0);
        }
    }
    #pragma unroll
    for (int i = 0; i < 4; i++){
        float inv = 1.f / li[i];
        size_t row = (size_t)b*1024 + q0 + (lane>>4)*4 + i;
        #pragma unroll
        for (int d = 0; d < 5; d++){
            int c = d*16 + (lane & 15);
            if (c < 72) o[row*1152 + h*72 + c] = f2bf(oa[d][i]*inv);
        }
    }
}

// ---------------- final: out = modulate(x, sh, sc) @ fin_w + fin_b (GEN rows) ----------------
__global__ __launch_bounds__(256) void final_k(const float* __restrict__ x,
    const float* __restrict__ modf, const float* __restrict__ finw,
    const float* __restrict__ finb, float* __restrict__ outp){
    __shared__ float yl[1152];
    __shared__ float ps[8][32];
    const int t = threadIdx.x;
    for (int r = 0; r < 8; r++){
        int gr = blockIdx.x*8 + r;              // 0..2047 GEN rows
        int b = gr >> 9, p = gr & 511;
        size_t m = (size_t)b*1024 + 512 + p;
        int mrow = 512 + b;
        const float* xr = x + m*1152;
        const float* md = modf + (size_t)mrow*2304;
        for (int c = t; c < 1152; c += 256)
            yl[c] = xr[c]*(1.f + md[1152 + c]) + md[c];
        __syncthreads();
        int j = t & 31, g = t >> 5;
        float s = 0.f;
        for (int c = g*144; c < g*144 + 144; c++) s += yl[c]*finw[c*32 + j];
        ps[g][j] = s;
        __syncthreads();
        if (t < 32){
            float acc = finb[j];
            #pragma unroll
            for (int gg = 0; gg < 8; gg++) acc += ps[gg][j];
            outp[((size_t)b*512 + p)*32 + j] = acc;
        }
        __syncthreads();
    }
}

// ---------------- host launch ----------------
extern "C" void kernel_launch(void* const* d_in, const int* in_sizes, int n_in,
                              void* d_out, int out_size, void* d_ws, size_t ws_size,
                              hipStream_t stream){
    const float* xin   = (const float*)d_in[0];
    const float* noise = (const float*)d_in[1];
    const float* rawh  = (const float*)d_in[2];
    const float* pose  = (const float*)d_in[4];
    const float* plug  = (const float*)d_in[5];
    const float* t_w0  = (const float*)d_in[6];
    const float* t_b0  = (const float*)d_in[7];
    const float* t_w2  = (const float*)d_in[8];
    const float* t_b2  = (const float*)d_in[9];
    const float* qkvw  = (const float*)d_in[10];
    const float* qkvb  = (const float*)d_in[11];
    const float* projw = (const float*)d_in[12];
    const float* projb = (const float*)d_in[13];
    const float* fc1w  = (const float*)d_in[14];
    const float* fc1b  = (const float*)d_in[15];
    const float* fc2w  = (const float*)d_in[16];
    const float* fc2b  = (const float*)d_in[17];
    const float* adaw  = (const float*)d_in[18];
    const float* adab  = (const float*)d_in[19];
    const float* finaw = (const float*)d_in[20];
    const float* finab = (const float*)d_in[21];
    const float* finw  = (const float*)d_in[22];
    const float* finb  = (const float*)d_in[23];

    char* ws = (char*)d_ws;
    float*          xbuf  = (float*)(ws + 0);                      // 4096x1152 f32   (18.87 MB)
    unsigned short* ybuf  = (unsigned short*)(ws + 18874368);      // 4096x1152 bf16  (9.44 MB)
    unsigned short* qh    = (unsigned short*)(ws + 28311552);      // 4096x4608 bf16  (37.75 MB)
    unsigned short* siluc = (unsigned short*)(ws + 66060288);      // 640x1152 bf16   (1.47 MB)
    float*          modb  = (float*)(ws + 67534848);               // 516x6912 f32    (14.27 MB)
    unsigned short* wt    = (unsigned short*)(ws + 81801216);      // <=6912x1152 bf16 (15.93 MB)

    silu_hist_k<<<2880,256,0,stream>>>(plug, siluc);
    cgen_k<<<4,576,0,stream>>>(noise, t_w0, t_b0, t_w2, t_b2, siluc);
    x0_k<<<4608,256,0,stream>>>(xin, rawh, pose, xbuf);

    for (int l = 0; l < 7; l++){
        // adaLN modulation GEMM (only 516 distinct c-rows)
        tw_k<<<dim3(216,36),256,0,stream>>>(adaw + (size_t)l*1152*6912, 1152, 6912, wt);
        gemm2_k<2><<<dim3(5,54),256,0,stream>>>(siluc,1152, wt,1152, adab + (size_t)l*6912,
            nullptr, modb, 6912, 516, 1152, nullptr, nullptr, 0, 0);
        ln_mod_k<<<4096,256,0,stream>>>(xbuf, modb, 6912, 0, ybuf);
        // qkv
        tw_k<<<dim3(108,36),256,0,stream>>>(qkvw + (size_t)l*1152*3456, 1152, 3456, wt);
        gemm2_k<0><<<dim3(32,27),256,0,stream>>>(ybuf,1152, wt,1152, qkvb + (size_t)l*3456,
            qh, nullptr, 3456, 4096, 1152, nullptr, nullptr, 0, 0);
        attn2_k<<<1024,256,0,stream>>>(qh, ybuf);
        // proj (+ gated residual into xbuf)
        tw_k<<<dim3(36,36),256,0,stream>>>(projw + (size_t)l*1152*1152, 1152, 1152, wt);
        gemm2_k<3><<<dim3(32,9),256,0,stream>>>(ybuf,1152, wt,1152, projb + (size_t)l*1152,
            nullptr, nullptr, 1152, 4096, 1152, xbuf, modb, 6912, 2304);
        ln_mod_k<<<4096,256,0,stream>>>(xbuf, modb, 6912, 3456, ybuf);
        // fc1 (gelu)
        tw_k<<<dim3(144,36),256,0,stream>>>(fc1w + (size_t)l*1152*4608, 1152, 4608, wt);
        gemm2_k<1><<<dim3(32,36),256,0,stream>>>(ybuf,1152, wt,1152, fc1b + (size_t)l*4608,
            qh, nullptr, 4608, 4096, 1152, nullptr, nullptr, 0, 0);
        // fc2 (+ gated residual into xbuf)
        tw_k<<<dim3(36,144),256,0,stream>>>(fc2w + (size_t)l*4608*1152, 4608, 1152, wt);
        gemm2_k<3><<<dim3(32,9),256,0,stream>>>(qh,4608, wt,4608, fc2b + (size_t)l*1152,
            nullptr, nullptr, 1152, 4096, 4608, xbuf, modb, 6912, 5760);
    }
    // final adaLN + projection
    tw_k<<<dim3(72,36),256,0,stream>>>(finaw, 1152, 2304, wt);
    gemm2_k<2><<<dim3(5,18),256,0,stream>>>(siluc,1152, wt,1152, finab,
        nullptr, modb, 2304, 516, 1152, nullptr, nullptr, 0, 0);
    final_k<<<256,256,0,stream>>>(xbuf, modb, finw, finb, (float*)d_out);
}

// Round 4
// 3499.035 us; speedup vs baseline: 1.6575x; 1.0241x over previous
//
#include <hip/hip_runtime.h>

// ---------------- types & helpers ----------------
typedef float f32x4 __attribute__((ext_vector_type(4)));
typedef __bf16 bf16x8 __attribute__((ext_vector_type(8)));
typedef unsigned short us8 __attribute__((ext_vector_type(8)));

static __device__ __forceinline__ unsigned short f2bf(float f){
    unsigned int u = __builtin_bit_cast(unsigned int, f);
    u += 0x7fffu + ((u >> 16) & 1u);
    return (unsigned short)(u >> 16);
}
static __device__ __forceinline__ bf16x8 ldb8(const unsigned short* p){
    return __builtin_bit_cast(bf16x8, *(const us8*)p);
}
typedef __attribute__((address_space(1))) void gas_void;
typedef __attribute__((address_space(3))) void las_void;
static __device__ __forceinline__ void gload_lds16(const void* g, void* l){
    __builtin_amdgcn_global_load_lds((gas_void*)g, (las_void*)l, 16, 0, 0);
}
static __device__ __forceinline__ float siluf(float v){
    return v / (1.f + __expf(-v));
}

// ---------------- prep: silu(plug_c_ref) rows 0..511, zero pad rows 512..639 ----------------
__global__ __launch_bounds__(256) void silu_hist_k(const float* __restrict__ plug,
                                                   unsigned short* __restrict__ siluc){
    int i = blockIdx.x*256 + threadIdx.x;
    if (i < 512*1152){
        siluc[i] = f2bf(siluf(plug[i]));
    } else if (i < 640*1152){
        siluc[i] = 0;   // pad rows: safe A-tile overread for M=516 GEMMs
    }
}

// ---------------- timestep MLP stage 1: hl[b][c] = silu(emb(b) @ t_w0 + b0) ----------------
__global__ __launch_bounds__(128) void cgen1_k(const float* __restrict__ noise,
    const float* __restrict__ t_w0, const float* __restrict__ t_b0,
    float* __restrict__ hl){
    __shared__ float emb[256];
    const int b = blockIdx.y;
    const int c = blockIdx.x*128 + threadIdx.x;     // 9 x 128 = 1152
    const float tv = noise[b];
    {
        int j = threadIdx.x;                         // 128 threads -> cos+sin each
        float arg = tv * __expf(-0.07195578415606394f * (float)j);
        emb[j] = cosf(arg);
        emb[128 + j] = sinf(arg);
    }
    __syncthreads();
    float s = t_b0[c];
    #pragma unroll 4
    for (int j = 0; j < 256; j++) s += emb[j] * t_w0[j*1152 + c];
    hl[b*1152 + c] = siluf(s);
}

// ---------------- timestep MLP stage 2: siluc[512+b][c] = silu(hl[b] @ t_w2 + b2) ----------------
__global__ __launch_bounds__(128) void cgen2_k(const float* __restrict__ hl,
    const float* __restrict__ t_w2, const float* __restrict__ t_b2,
    unsigned short* __restrict__ siluc){
    __shared__ float h[1152];
    const int b = blockIdx.y;
    const int c = blockIdx.x*128 + threadIdx.x;
    for (int j = threadIdx.x; j < 1152; j += 128) h[j] = hl[b*1152 + j];
    __syncthreads();
    float s = t_b2[c];
    #pragma unroll 4
    for (int j = 0; j < 1152; j++) s += h[j] * t_w2[j*1152 + c];
    siluc[(size_t)(512 + b)*1152 + c] = f2bf(siluf(s));
}

// ---------------- prep: x0 = tile(concat(rawhist,x),36) + pos_embed ----------------
__global__ __launch_bounds__(256) void x0_k(const float* __restrict__ xg,
    const float* __restrict__ rh, const float* __restrict__ pe, float* __restrict__ x){
    int i4 = blockIdx.x*256 + threadIdx.x;          // float4 index
    if (i4 >= 1179648) return;                      // 4096*1152/4
    int m = i4 / 288;
    int c = (i4 - m*288) * 4;
    int pos = m & 1023, b = m >> 10;
    const float* src = (pos < 512) ? (rh + ((size_t)b*512 + pos)*32)
                                   : (xg + ((size_t)b*512 + (pos-512))*32);
    float4 sv = *(const float4*)(src + (c & 31));
    float4 pv = *(const float4*)(pe + (size_t)pos*1152 + c);
    float4 o; o.x = sv.x+pv.x; o.y = sv.y+pv.y; o.z = sv.z+pv.z; o.w = sv.w+pv.w;
    *(float4*)(x + (size_t)i4*4) = o;
}

// ---------------- weight transpose-convert: W f32 [K][N] -> Wt bf16 [N][K] ----------------
__global__ __launch_bounds__(256) void tw_k(const float* __restrict__ W, int Kd, int Nd,
                                            unsigned short* __restrict__ Wt){
    __shared__ float tile[32][33];
    int n0 = blockIdx.x*32, k0 = blockIdx.y*32;
    int t = threadIdx.x;
    #pragma unroll
    for (int i = 0; i < 4; i++){
        int idx = t + 256*i;
        int kk = idx >> 5, nn = idx & 31;
        tile[kk][nn] = W[(size_t)(k0+kk)*Nd + n0+nn];
    }
    __syncthreads();
    #pragma unroll
    for (int i = 0; i < 4; i++){
        int idx = t + 256*i;
        int nn = idx >> 5, kk = idx & 31;
        Wt[(size_t)(n0+nn)*Kd + k0+kk] = f2bf(tile[kk][nn]);
    }
}

// ---------------- merged per-layer transpose: all 5 weights in one launch ----------------
// tiles: ada 216x36=7776 | qkv 108x36=3888 | proj 36x36=1296 | fc1 144x36=5184 | fc2 36x144=5184
__global__ __launch_bounds__(256) void tw5_k(const float* __restrict__ w0,
    const float* __restrict__ w1, const float* __restrict__ w2,
    const float* __restrict__ w3, const float* __restrict__ w4,
    unsigned short* __restrict__ wt){
    __shared__ float tile[32][33];
    const int cum[5]  = {7776, 11664, 12960, 18144, 23328};
    const int kds[5]  = {1152, 1152, 1152, 1152, 4608};
    const int nds[5]  = {6912, 3456, 1152, 4608, 1152};
    const size_t dof[5] = {0ul, 7962624ul, 11943936ul, 13271040ul, 18579456ul};
    int bid = blockIdx.x;
    int w = (bid < cum[1]) ? ((bid < cum[0]) ? 0 : 1)
                           : ((bid < cum[2]) ? 2 : (bid < cum[3]) ? 3 : 4);
    int local = bid - (w ? cum[w-1] : 0);
    const float* W = (w==0)?w0:(w==1)?w1:(w==2)?w2:(w==3)?w3:w4;
    unsigned short* Wt = wt + dof[w];
    const int Kd = kds[w], Nd = nds[w];
    const int ntx = Nd >> 5;
    const int n0 = (local % ntx)*32, k0 = (local / ntx)*32;
    const int t = threadIdx.x;
    #pragma unroll
    for (int i = 0; i < 4; i++){
        int idx = t + 256*i;
        int kk = idx >> 5, nn = idx & 31;
        tile[kk][nn] = W[(size_t)(k0+kk)*Nd + n0+nn];
    }
    __syncthreads();
    #pragma unroll
    for (int i = 0; i < 4; i++){
        int idx = t + 256*i;
        int nn = idx >> 5, kk = idx & 31;
        Wt[(size_t)(n0+nn)*Kd + k0+kk] = f2bf(tile[kk][nn]);
    }
}

// ---------------- LN (no affine) + modulate -> bf16 ----------------
__global__ __launch_bounds__(256) void ln_mod_k(const float* __restrict__ x,
    const float* __restrict__ modb, int mld, int ofs, unsigned short* __restrict__ y){
    const int m = blockIdx.x, t = threadIdx.x;
    const int lane = t & 63, wv = t >> 6;
    const float* xr = x + (size_t)m*1152;
    float4 v0 = ((const float4*)xr)[t];
    float4 v1 = {0.f,0.f,0.f,0.f};
    bool h2 = (t < 32);
    if (h2) v1 = ((const float4*)xr)[256 + t];
    float s = v0.x+v0.y+v0.z+v0.w + v1.x+v1.y+v1.z+v1.w;
    float q = v0.x*v0.x+v0.y*v0.y+v0.z*v0.z+v0.w*v0.w
            + v1.x*v1.x+v1.y*v1.y+v1.z*v1.z+v1.w*v1.w;
    #pragma unroll
    for (int o = 32; o; o >>= 1){ s += __shfl_xor(s,o); q += __shfl_xor(q,o); }
    __shared__ float red[8];
    if (lane == 0){ red[wv] = s; red[4+wv] = q; }
    __syncthreads();
    s = red[0]+red[1]+red[2]+red[3];
    q = red[4]+red[5]+red[6]+red[7];
    const float mean = s * (1.f/1152.f);
    const float var  = q * (1.f/1152.f) - mean*mean;
    const float rstd = rsqrtf(var + 1e-6f);
    const int pos = m & 1023, bb = m >> 10;
    const int mrow = (pos < 512) ? pos : (512 + bb);
    const float* sh = modb + (size_t)mrow*mld + ofs;
    const float* sc = sh + 1152;
    {
        int c = t*4;
        float4 shv = *(const float4*)(sh + c);
        float4 scv = *(const float4*)(sc + c);
        ushort4 o4;
        o4.x = f2bf((v0.x-mean)*rstd*(1.f+scv.x) + shv.x);
        o4.y = f2bf((v0.y-mean)*rstd*(1.f+scv.y) + shv.y);
        o4.z = f2bf((v0.z-mean)*rstd*(1.f+scv.z) + shv.z);
        o4.w = f2bf((v0.w-mean)*rstd*(1.f+scv.w) + shv.w);
        *(ushort4*)(y + (size_t)m*1152 + c) = o4;
    }
    if (h2){
        int c = 1024 + t*4;
        float4 shv = *(const float4*)(sh + c);
        float4 scv = *(const float4*)(sc + c);
        ushort4 o4;
        o4.x = f2bf((v1.x-mean)*rstd*(1.f+scv.x) + shv.x);
        o4.y = f2bf((v1.y-mean)*rstd*(1.f+scv.y) + shv.y);
        o4.z = f2bf((v1.z-mean)*rstd*(1.f+scv.z) + shv.z);
        o4.w = f2bf((v1.w-mean)*rstd*(1.f+scv.w) + shv.w);
        *(ushort4*)(y + (size_t)m*1152 + c) = o4;
    }
}

// ---------------- GEMM (m97 structure): out = epi(A(bf16,MxK) @ Wt^T + bias) ----------------
// A row-major [M][K] lda; B = Wt row-major [N][K] ldb. Both staged via global_load_lds.
// EPI: 0 = bf16 store, 1 = gelu->bf16, 2 = f32 store (guard row<M), 3 = x += gate*(v)
template<int EPI>
__global__ __launch_bounds__(256,2)
void gemm2_k(const unsigned short* __restrict__ A, int lda,
             const unsigned short* __restrict__ B, int ldb,
             const float* __restrict__ bias,
             unsigned short* __restrict__ outb, float* __restrict__ outf, int ldo,
             int M, int K,
             float* __restrict__ xres,
             const float* __restrict__ modb, int mld, int gofs){
    __shared__ unsigned short Alds[128*32];
    __shared__ unsigned short Blds[128*32];
    const int tid  = threadIdx.x;
    const int lane = tid & 63;
    const int wv   = tid >> 6;
    const int wr   = wv >> 1, wc = wv & 1;
    const int m0 = blockIdx.x * 128;          // M fastest -> same-W-panel blocks cluster
    const int n0 = blockIdx.y * 128;

    const int r0 = (wv*2 + 0)*16 + (lane >> 2);
    const int r1 = (wv*2 + 1)*16 + (lane >> 2);
    const unsigned short* ag0 = A + (size_t)(m0 + r0)*lda + (lane & 3)*8;
    const unsigned short* ag1 = A + (size_t)(m0 + r1)*lda + (lane & 3)*8;
    const unsigned short* bg0 = B + (size_t)(n0 + r0)*ldb + (lane & 3)*8;
    const unsigned short* bg1 = B + (size_t)(n0 + r1)*ldb + (lane & 3)*8;
    unsigned short* al0 = &Alds[(wv*2 + 0)*512];
    unsigned short* al1 = &Alds[(wv*2 + 1)*512];
    unsigned short* bl0 = &Blds[(wv*2 + 0)*512];
    unsigned short* bl1 = &Blds[(wv*2 + 1)*512];

    f32x4 acc[4][4];
    #pragma unroll
    for (int i = 0; i < 4; i++)
        #pragma unroll
        for (int j = 0; j < 4; j++){ f32x4 z = {0.f,0.f,0.f,0.f}; acc[i][j] = z; }

    for (int ks = 0; ks < K; ks += 32){
        if (ks) __syncthreads();
        gload_lds16((const void*)ag0, (void*)al0);
        gload_lds16((const void*)ag1, (void*)al1);
        gload_lds16((const void*)bg0, (void*)bl0);
        gload_lds16((const void*)bg1, (void*)bl1);
        ag0 += 32; ag1 += 32; bg0 += 32; bg1 += 32;
        __syncthreads();
        bf16x8 af[4], bfm[4];
        #pragma unroll
        for (int mt = 0; mt < 4; mt++)
            af[mt] = ldb8(&Alds[(wr*64 + mt*16 + (lane&15))*32 + (lane>>4)*8]);
        #pragma unroll
        for (int nt = 0; nt < 4; nt++)
            bfm[nt] = ldb8(&Blds[(wc*64 + nt*16 + (lane&15))*32 + (lane>>4)*8]);
        #pragma unroll
        for (int mt = 0; mt < 4; mt++)
            #pragma unroll
            for (int nt = 0; nt < 4; nt++)
                acc[mt][nt] = __builtin_amdgcn_mfma_f32_16x16x32_bf16(af[mt], bfm[nt], acc[mt][nt], 0,0,0);
    }

    const int cb = n0 + wc*64;
    const int rb = m0 + wr*64;
    #pragma unroll
    for (int nt = 0; nt < 4; nt++){
        int col = cb + nt*16 + (lane & 15);
        float bn = bias[col];
        #pragma unroll
        for (int mt = 0; mt < 4; mt++){
            #pragma unroll
            for (int i = 0; i < 4; i++){
                int row = rb + mt*16 + (lane>>4)*4 + i;
                float v = acc[mt][nt][i] + bn;
                if (EPI == 0){
                    outb[(size_t)row*ldo + col] = f2bf(v);
                } else if (EPI == 1){
                    float z = 0.7978845608f*(v + 0.044715f*v*v*v);
                    float e = __expf(-2.f*fabsf(z));
                    float th = (1.f - e)/(1.f + e);
                    th = (z >= 0.f) ? th : -th;
                    outb[(size_t)row*ldo + col] = f2bf(0.5f*v*(1.f + th));
                } else if (EPI == 2){
                    if (row < M) outf[(size_t)row*ldo + col] = v;
                } else {
                    int pos = row & 1023, bb2 = row >> 10;
                    int mrow = (pos < 512) ? pos : (512 + bb2);
                    float g = modb[(size_t)mrow*mld + gofs + col];
                    xres[(size_t)row*1152 + col] += g * v;
                }
            }
        }
    }
}

// ---------------- flash attention v2: 4 waves/block, 64 q rows, shared K + transposed V ----------------
__global__ __launch_bounds__(256)
void attn2_k(const unsigned short* __restrict__ qkv, unsigned short* __restrict__ o){
    __shared__ unsigned short Q[64*104];      // padded pitch 104 (52 words)
    __shared__ unsigned short Kl[32*104];
    __shared__ unsigned short Vt[96*40];      // V transposed [d][kv], pitch 40 (20 words)
    __shared__ unsigned short Pl[4][16*40];   // per-wave P, pitch 40
    const int tid  = threadIdx.x;
    const int lane = tid & 63;
    const int w    = tid >> 6;
    const int qb = blockIdx.x & 15;
    const int bh = blockIdx.x >> 4;
    const int h = bh & 15, b = bh >> 4;
    const size_t base = (size_t)b*1024*3456;
    const int qcol = h*72, kcol = 1152 + h*72, vcol = 2304 + h*72;

    {   // zero pads once: Q cols 72..103, K cols 72..103, Vt rows 72..95
        ushort4 z4 = {0,0,0,0};
        for (int i = tid; i < 512; i += 256){ int r = i>>3, j = i&7; *(ushort4*)&Q[r*104 + 72 + j*4] = z4; }
        { int i = tid; if (i < 256){ int r = i>>3, j = i&7; *(ushort4*)&Kl[r*104 + 72 + j*4] = z4; } }
        { int i = tid; if (i < 240){ int r = 72 + i/10, j = i - (i/10)*10; *(ushort4*)&Vt[r*40 + j*4] = z4; } }
    }
    // Q: 64 rows x 72 cols, ushort4 chunks
    for (int ch = tid; ch < 1152; ch += 256){
        int r = ch/18, d4 = (ch - r*18)*4;
        *(ushort4*)&Q[r*104 + d4] = *(const ushort4*)(qkv + base + (size_t)(qb*64 + r)*3456 + qcol + d4);
    }

    float mi[4], li[4];
    f32x4 oa[5];
    #pragma unroll
    for (int i = 0; i < 4; i++){ mi[i] = -INFINITY; li[i] = 0.f; }
    #pragma unroll
    for (int d = 0; d < 5; d++){ f32x4 z = {0.f,0.f,0.f,0.f}; oa[d] = z; }

    const int q0 = qb*64 + w*16;              // this wave's first q row (absolute)
    const int ktmax = 2*qb + 2;
    const float qsc = 0.11785113019775793f;   // 72^-0.5

    for (int kt = 0; kt < ktmax; kt++){
        const int kvb = kt*32;
        __syncthreads();
        for (int ch = tid; ch < 576; ch += 256){
            int r = ch/18, d4 = (ch - r*18)*4;
            size_t g = base + (size_t)(kvb + r)*3456 + d4;
            *(ushort4*)&Kl[r*104 + d4] = *(const ushort4*)(qkv + g + kcol);
            ushort4 vv = *(const ushort4*)(qkv + g + vcol);
            Vt[(d4+0)*40 + r] = vv.x;
            Vt[(d4+1)*40 + r] = vv.y;
            Vt[(d4+2)*40 + r] = vv.z;
            Vt[(d4+3)*40 + r] = vv.w;
        }
        __syncthreads();
        if (kvb > q0 + 15) continue;          // wave-uniform skip (no barriers inside)

        f32x4 s0 = {0.f,0.f,0.f,0.f}, s1 = {0.f,0.f,0.f,0.f};
        const unsigned short* Qw = &Q[(w*16)*104];
        #pragma unroll
        for (int st = 0; st < 3; st++){
            bf16x8 aq = ldb8(&Qw[(lane&15)*104 + (lane>>4)*8 + st*32]);
            bf16x8 k0 = ldb8(&Kl[(lane&15)*104 + (lane>>4)*8 + st*32]);
            bf16x8 k1 = ldb8(&Kl[(16+(lane&15))*104 + (lane>>4)*8 + st*32]);
            s0 = __builtin_amdgcn_mfma_f32_16x16x32_bf16(aq, k0, s0, 0,0,0);
            s1 = __builtin_amdgcn_mfma_f32_16x16x32_bf16(aq, k1, s1, 0,0,0);
        }
        const bool domask = (kvb + 31 > q0);
        float p0[4], p1[4];
        #pragma unroll
        for (int i = 0; i < 4; i++){
            float a = s0[i]*qsc, c = s1[i]*qsc;
            if (domask){
                int r = q0 + (lane>>4)*4 + i;
                if (kvb + (lane&15) > r) a = -1e30f;
                if (kvb + 16 + (lane&15) > r) c = -1e30f;
            }
            float pm = fmaxf(a, c);
            #pragma unroll
            for (int off = 1; off < 16; off <<= 1) pm = fmaxf(pm, __shfl_xor(pm, off));
            float nm = fmaxf(mi[i], pm);
            float f = __expf(mi[i] - nm);
            mi[i] = nm;
            a = __expf(a - nm); c = __expf(c - nm);
            float rs = a + c;
            #pragma unroll
            for (int off = 1; off < 16; off <<= 1) rs += __shfl_xor(rs, off);
            li[i] = li[i]*f + rs;
            #pragma unroll
            for (int d = 0; d < 5; d++) oa[d][i] *= f;
            p0[i] = a; p1[i] = c;
        }
        unsigned short* Pw = Pl[w];
        #pragma unroll
        for (int i = 0; i < 4; i++){
            int r = (lane>>4)*4 + i;
            Pw[r*40 + (lane&15)]      = f2bf(p0[i]);
            Pw[r*40 + 16 + (lane&15)] = f2bf(p1[i]);
        }
        bf16x8 pa = ldb8(&Pw[(lane&15)*40 + (lane>>4)*8]);
        #pragma unroll
        for (int d = 0; d < 5; d++){
            bf16x8 bv = ldb8(&Vt[(d*16 + (lane&15))*40 + (lane>>4)*8]);
            oa[d] = __builtin_amdgcn_mfma_f32_16x16x32_bf16(pa, bv, oa[d], 0,0,0);
        }
    }
    #pragma unroll
    for (int i = 0; i < 4; i++){
        float inv = 1.f / li[i];
        size_t row = (size_t)b*1024 + q0 + (lane>>4)*4 + i;
        #pragma unroll
        for (int d = 0; d < 5; d++){
            int c = d*16 + (lane & 15);
            if (c < 72) o[row*1152 + h*72 + c] = f2bf(oa[d][i]*inv);
        }
    }
}

// ---------------- final: out = modulate(x, sh, sc) @ fin_w + fin_b (GEN rows) ----------------
__global__ __launch_bounds__(256) void final_k(const float* __restrict__ x,
    const float* __restrict__ modf, const float* __restrict__ finw,
    const float* __restrict__ finb, float* __restrict__ outp){
    __shared__ float yl[1152];
    __shared__ float ps[8][32];
    const int t = threadIdx.x;
    for (int r = 0; r < 8; r++){
        int gr = blockIdx.x*8 + r;              // 0..2047 GEN rows
        int b = gr >> 9, p = gr & 511;
        size_t m = (size_t)b*1024 + 512 + p;
        int mrow = 512 + b;
        const float* xr = x + m*1152;
        const float* md = modf + (size_t)mrow*2304;
        for (int c = t; c < 1152; c += 256)
            yl[c] = xr[c]*(1.f + md[1152 + c]) + md[c];
        __syncthreads();
        int j = t & 31, g = t >> 5;
        float s = 0.f;
        for (int c = g*144; c < g*144 + 144; c++) s += yl[c]*finw[c*32 + j];
        ps[g][j] = s;
        __syncthreads();
        if (t < 32){
            float acc = finb[j];
            #pragma unroll
            for (int gg = 0; gg < 8; gg++) acc += ps[gg][j];
            outp[((size_t)b*512 + p)*32 + j] = acc;
        }
        __syncthreads();
    }
}

// ---------------- host launch ----------------
extern "C" void kernel_launch(void* const* d_in, const int* in_sizes, int n_in,
                              void* d_out, int out_size, void* d_ws, size_t ws_size,
                              hipStream_t stream){
    const float* xin   = (const float*)d_in[0];
    const float* noise = (const float*)d_in[1];
    const float* rawh  = (const float*)d_in[2];
    const float* pose  = (const float*)d_in[4];
    const float* plug  = (const float*)d_in[5];
    const float* t_w0  = (const float*)d_in[6];
    const float* t_b0  = (const float*)d_in[7];
    const float* t_w2  = (const float*)d_in[8];
    const float* t_b2  = (const float*)d_in[9];
    const float* qkvw  = (const float*)d_in[10];
    const float* qkvb  = (const float*)d_in[11];
    const float* projw = (const float*)d_in[12];
    const float* projb = (const float*)d_in[13];
    const float* fc1w  = (const float*)d_in[14];
    const float* fc1b  = (const float*)d_in[15];
    const float* fc2w  = (const float*)d_in[16];
    const float* fc2b  = (const float*)d_in[17];
    const float* adaw  = (const float*)d_in[18];
    const float* adab  = (const float*)d_in[19];
    const float* finaw = (const float*)d_in[20];
    const float* finab = (const float*)d_in[21];
    const float* finw  = (const float*)d_in[22];
    const float* finb  = (const float*)d_in[23];

    char* ws = (char*)d_ws;
    float*          xbuf  = (float*)(ws + 0);                      // 4096x1152 f32   (18.87 MB)
    unsigned short* ybuf  = (unsigned short*)(ws + 18874368);      // 4096x1152 bf16  (9.44 MB)
    unsigned short* qh    = (unsigned short*)(ws + 28311552);      // 4096x4608 bf16  (37.75 MB)
    unsigned short* siluc = (unsigned short*)(ws + 66060288);      // 640x1152 bf16   (1.47 MB)
    float*          modb  = (float*)(ws + 67534848);               // 516x6912 f32    (14.27 MB)
    unsigned short* wt    = (unsigned short*)(ws + 81801216);      // merged: 47.78 MB / fallback: 15.93 MB
    float*          hl    = (float*)qh;                            // 4x1152 f32, dead before qkv gemm

    const bool merged = (ws_size >= 129576960ul);

    silu_hist_k<<<2880,256,0,stream>>>(plug, siluc);
    cgen1_k<<<dim3(9,4),128,0,stream>>>(noise, t_w0, t_b0, hl);
    cgen2_k<<<dim3(9,4),128,0,stream>>>(hl, t_w2, t_b2, siluc);
    x0_k<<<4608,256,0,stream>>>(xin, rawh, pose, xbuf);

    // wt sub-offsets (bf16 elements) for merged layout
    unsigned short* wt_ada = wt;
    unsigned short* wt_qkv = merged ? wt +  7962624 : wt;
    unsigned short* wt_prj = merged ? wt + 11943936 : wt;
    unsigned short* wt_fc1 = merged ? wt + 13271040 : wt;
    unsigned short* wt_fc2 = merged ? wt + 18579456 : wt;

    for (int l = 0; l < 7; l++){
        if (merged){
            tw5_k<<<23328,256,0,stream>>>(adaw + (size_t)l*1152*6912, qkvw + (size_t)l*1152*3456,
                projw + (size_t)l*1152*1152, fc1w + (size_t)l*1152*4608,
                fc2w + (size_t)l*4608*1152, wt);
        } else {
            tw_k<<<dim3(216,36),256,0,stream>>>(adaw + (size_t)l*1152*6912, 1152, 6912, wt);
        }
        gemm2_k<2><<<dim3(5,54),256,0,stream>>>(siluc,1152, wt_ada,1152, adab + (size_t)l*6912,
            nullptr, modb, 6912, 516, 1152, nullptr, nullptr, 0, 0);
        ln_mod_k<<<4096,256,0,stream>>>(xbuf, modb, 6912, 0, ybuf);
        // qkv
        if (!merged) tw_k<<<dim3(108,36),256,0,stream>>>(qkvw + (size_t)l*1152*3456, 1152, 3456, wt);
        gemm2_k<0><<<dim3(32,27),256,0,stream>>>(ybuf,1152, wt_qkv,1152, qkvb + (size_t)l*3456,
            qh, nullptr, 3456, 4096, 1152, nullptr, nullptr, 0, 0);
        attn2_k<<<1024,256,0,stream>>>(qh, ybuf);
        // proj (+ gated residual into xbuf)
        if (!merged) tw_k<<<dim3(36,36),256,0,stream>>>(projw + (size_t)l*1152*1152, 1152, 1152, wt);
        gemm2_k<3><<<dim3(32,9),256,0,stream>>>(ybuf,1152, wt_prj,1152, projb + (size_t)l*1152,
            nullptr, nullptr, 1152, 4096, 1152, xbuf, modb, 6912, 2304);
        ln_mod_k<<<4096,256,0,stream>>>(xbuf, modb, 6912, 3456, ybuf);
        // fc1 (gelu)
        if (!merged) tw_k<<<dim3(144,36),256,0,stream>>>(fc1w + (size_t)l*1152*4608, 1152, 4608, wt);
        gemm2_k<1><<<dim3(32,36),256,0,stream>>>(ybuf,1152, wt_fc1,1152, fc1b + (size_t)l*4608,
            qh, nullptr, 4608, 4096, 1152, nullptr, nullptr, 0, 0);
        // fc2 (+ gated residual into xbuf)
        if (!merged) tw_k<<<dim3(36,144),256,0,stream>>>(fc2w + (size_t)l*4608*1152, 4608, 1152, wt);
        gemm2_k<3><<<dim3(32,9),256,0,stream>>>(qh,4608, wt_fc2,4608, fc2b + (size_t)l*1152,
            nullptr, nullptr, 1152, 4096, 4608, xbuf, modb, 6912, 5760);
    }
    // final adaLN + projection
    tw_k<<<dim3(72,36),256,0,stream>>>(finaw, 1152, 2304, wt);
    gemm2_k<2><<<dim3(5,18),256,0,stream>>>(siluc,1152, wt,1152, finab,
        nullptr, modb, 2304, 516, 1152, nullptr, nullptr, 0, 0);
    final_k<<<256,256,0,stream>>>(xbuf, modb, finw, finb, (float*)d_out);
}

// Round 5
// 3322.684 us; speedup vs baseline: 1.7455x; 1.0531x over previous
//
#include <hip/hip_runtime.h>

// ---------------- types & helpers ----------------
typedef float f32x4 __attribute__((ext_vector_type(4)));
typedef __bf16 bf16x8 __attribute__((ext_vector_type(8)));
typedef unsigned short us8 __attribute__((ext_vector_type(8)));

static __device__ __forceinline__ unsigned short f2bf(float f){
    unsigned int u = __builtin_bit_cast(unsigned int, f);
    u += 0x7fffu + ((u >> 16) & 1u);
    return (unsigned short)(u >> 16);
}
static __device__ __forceinline__ bf16x8 ldb8(const unsigned short* p){
    return __builtin_bit_cast(bf16x8, *(const us8*)p);
}
typedef __attribute__((address_space(1))) void gas_void;
typedef __attribute__((address_space(3))) void las_void;
static __device__ __forceinline__ void gload_lds16(const void* g, void* l){
    __builtin_amdgcn_global_load_lds((gas_void*)g, (las_void*)l, 16, 0, 0);
}
static __device__ __forceinline__ float siluf(float v){
    return v / (1.f + __expf(-v));
}

// ---------------- prep: silu(plug_c_ref) rows 0..511, zero pad rows 512..639 ----------------
__global__ __launch_bounds__(256) void silu_hist_k(const float* __restrict__ plug,
                                                   unsigned short* __restrict__ siluc){
    int i = blockIdx.x*256 + threadIdx.x;
    if (i < 512*1152){
        siluc[i] = f2bf(siluf(plug[i]));
    } else if (i < 640*1152){
        siluc[i] = 0;   // pad rows: safe A-tile overread for M=516 GEMMs
    }
}

// ---------------- timestep MLP stage 1 (split-K x4): hl = silu(emb @ t_w0 + b0) ----------------
__global__ __launch_bounds__(256) void cgen1_k(const float* __restrict__ noise,
    const float* __restrict__ t_w0, const float* __restrict__ t_b0,
    float* __restrict__ hl){
    __shared__ float emb[256];
    __shared__ float part[4][64];
    const int t = threadIdx.x;
    const int b = blockIdx.y;
    const int c = blockIdx.x*64 + (t & 63);
    const int kg = t >> 6;
    const float tv = noise[b];
    if (t < 128){
        float arg = tv * __expf(-0.07195578415606394f * (float)t);
        emb[t] = cosf(arg);
        emb[128 + t] = sinf(arg);
    }
    __syncthreads();
    float s = 0.f;
    #pragma unroll 4
    for (int j = kg*64; j < kg*64 + 64; j++) s += emb[j] * t_w0[j*1152 + c];
    part[kg][t & 63] = s;
    __syncthreads();
    if (t < 64){
        float v = part[0][t] + part[1][t] + part[2][t] + part[3][t] + t_b0[c];
        hl[b*1152 + c] = siluf(v);
    }
}

// ---------------- timestep MLP stage 2 (split-K x4): siluc[512+b] = silu(hl @ t_w2 + b2) ----------------
__global__ __launch_bounds__(256) void cgen2_k(const float* __restrict__ hl,
    const float* __restrict__ t_w2, const float* __restrict__ t_b2,
    unsigned short* __restrict__ siluc){
    __shared__ float h[1152];
    __shared__ float part[4][64];
    const int t = threadIdx.x;
    const int b = blockIdx.y;
    const int c = blockIdx.x*64 + (t & 63);
    const int kg = t >> 6;
    for (int j = t; j < 1152; j += 256) h[j] = hl[b*1152 + j];
    __syncthreads();
    float s = 0.f;
    #pragma unroll 4
    for (int j = kg*288; j < kg*288 + 288; j++) s += h[j] * t_w2[j*1152 + c];
    part[kg][t & 63] = s;
    __syncthreads();
    if (t < 64){
        float v = part[0][t] + part[1][t] + part[2][t] + part[3][t] + t_b2[c];
        siluc[(size_t)(512 + b)*1152 + c] = f2bf(siluf(v));
    }
}

// ---------------- prep: x0 = tile(concat(rawhist,x),36) + pos_embed ----------------
__global__ __launch_bounds__(256) void x0_k(const float* __restrict__ xg,
    const float* __restrict__ rh, const float* __restrict__ pe, float* __restrict__ x){
    int i4 = blockIdx.x*256 + threadIdx.x;          // float4 index
    if (i4 >= 1179648) return;                      // 4096*1152/4
    int m = i4 / 288;
    int c = (i4 - m*288) * 4;
    int pos = m & 1023, b = m >> 10;
    const float* src = (pos < 512) ? (rh + ((size_t)b*512 + pos)*32)
                                   : (xg + ((size_t)b*512 + (pos-512))*32);
    float4 sv = *(const float4*)(src + (c & 31));
    float4 pv = *(const float4*)(pe + (size_t)pos*1152 + c);
    float4 o; o.x = sv.x+pv.x; o.y = sv.y+pv.y; o.z = sv.z+pv.z; o.w = sv.w+pv.w;
    *(float4*)(x + (size_t)i4*4) = o;
}

// ---------------- weight transpose-convert: W f32 [K][N] -> Wt bf16 [N][K] ----------------
__global__ __launch_bounds__(256) void tw_k(const float* __restrict__ W, int Kd, int Nd,
                                            unsigned short* __restrict__ Wt){
    __shared__ float tile[32][33];
    int n0 = blockIdx.x*32, k0 = blockIdx.y*32;
    int t = threadIdx.x;
    #pragma unroll
    for (int i = 0; i < 4; i++){
        int idx = t + 256*i;
        int kk = idx >> 5, nn = idx & 31;
        tile[kk][nn] = W[(size_t)(k0+kk)*Nd + n0+nn];
    }
    __syncthreads();
    #pragma unroll
    for (int i = 0; i < 4; i++){
        int idx = t + 256*i;
        int nn = idx >> 5, kk = idx & 31;
        Wt[(size_t)(n0+nn)*Kd + k0+kk] = f2bf(tile[kk][nn]);
    }
}

// ---------------- merged per-layer transpose: all 5 weights in one launch ----------------
// tiles: ada 216x36=7776 | qkv 108x36=3888 | proj 36x36=1296 | fc1 144x36=5184 | fc2 36x144=5184
__global__ __launch_bounds__(256) void tw5_k(const float* __restrict__ w0,
    const float* __restrict__ w1, const float* __restrict__ w2,
    const float* __restrict__ w3, const float* __restrict__ w4,
    unsigned short* __restrict__ wt){
    __shared__ float tile[32][33];
    const int cum[5]  = {7776, 11664, 12960, 18144, 23328};
    const int kds[5]  = {1152, 1152, 1152, 1152, 4608};
    const int nds[5]  = {6912, 3456, 1152, 4608, 1152};
    const size_t dof[5] = {0ul, 7962624ul, 11943936ul, 13271040ul, 18579456ul};
    int bid = blockIdx.x;
    int w = (bid < cum[1]) ? ((bid < cum[0]) ? 0 : 1)
                           : ((bid < cum[2]) ? 2 : (bid < cum[3]) ? 3 : 4);
    int local = bid - (w ? cum[w-1] : 0);
    const float* W = (w==0)?w0:(w==1)?w1:(w==2)?w2:(w==3)?w3:w4;
    unsigned short* Wt = wt + dof[w];
    const int Kd = kds[w], Nd = nds[w];
    const int ntx = Nd >> 5;
    const int n0 = (local % ntx)*32, k0 = (local / ntx)*32;
    const int t = threadIdx.x;
    #pragma unroll
    for (int i = 0; i < 4; i++){
        int idx = t + 256*i;
        int kk = idx >> 5, nn = idx & 31;
        tile[kk][nn] = W[(size_t)(k0+kk)*Nd + n0+nn];
    }
    __syncthreads();
    #pragma unroll
    for (int i = 0; i < 4; i++){
        int idx = t + 256*i;
        int nn = idx >> 5, kk = idx & 31;
        Wt[(size_t)(n0+nn)*Kd + k0+kk] = f2bf(tile[kk][nn]);
    }
}

// ---------------- LN (no affine) + modulate -> bf16 ----------------
__global__ __launch_bounds__(256) void ln_mod_k(const float* __restrict__ x,
    const float* __restrict__ modb, int mld, int ofs, unsigned short* __restrict__ y){
    const int m = blockIdx.x, t = threadIdx.x;
    const int lane = t & 63, wv = t >> 6;
    const float* xr = x + (size_t)m*1152;
    float4 v0 = ((const float4*)xr)[t];
    float4 v1 = {0.f,0.f,0.f,0.f};
    bool h2 = (t < 32);
    if (h2) v1 = ((const float4*)xr)[256 + t];
    float s = v0.x+v0.y+v0.z+v0.w + v1.x+v1.y+v1.z+v1.w;
    float q = v0.x*v0.x+v0.y*v0.y+v0.z*v0.z+v0.w*v0.w
            + v1.x*v1.x+v1.y*v1.y+v1.z*v1.z+v1.w*v1.w;
    #pragma unroll
    for (int o = 32; o; o >>= 1){ s += __shfl_xor(s,o); q += __shfl_xor(q,o); }
    __shared__ float red[8];
    if (lane == 0){ red[wv] = s; red[4+wv] = q; }
    __syncthreads();
    s = red[0]+red[1]+red[2]+red[3];
    q = red[4]+red[5]+red[6]+red[7];
    const float mean = s * (1.f/1152.f);
    const float var  = q * (1.f/1152.f) - mean*mean;
    const float rstd = rsqrtf(var + 1e-6f);
    const int pos = m & 1023, bb = m >> 10;
    const int mrow = (pos < 512) ? pos : (512 + bb);
    const float* sh = modb + (size_t)mrow*mld + ofs;
    const float* sc = sh + 1152;
    {
        int c = t*4;
        float4 shv = *(const float4*)(sh + c);
        float4 scv = *(const float4*)(sc + c);
        ushort4 o4;
        o4.x = f2bf((v0.x-mean)*rstd*(1.f+scv.x) + shv.x);
        o4.y = f2bf((v0.y-mean)*rstd*(1.f+scv.y) + shv.y);
        o4.z = f2bf((v0.z-mean)*rstd*(1.f+scv.z) + shv.z);
        o4.w = f2bf((v0.w-mean)*rstd*(1.f+scv.w) + shv.w);
        *(ushort4*)(y + (size_t)m*1152 + c) = o4;
    }
    if (h2){
        int c = 1024 + t*4;
        float4 shv = *(const float4*)(sh + c);
        float4 scv = *(const float4*)(sc + c);
        ushort4 o4;
        o4.x = f2bf((v1.x-mean)*rstd*(1.f+scv.x) + shv.x);
        o4.y = f2bf((v1.y-mean)*rstd*(1.f+scv.y) + shv.y);
        o4.z = f2bf((v1.z-mean)*rstd*(1.f+scv.z) + shv.z);
        o4.w = f2bf((v1.w-mean)*rstd*(1.f+scv.w) + shv.w);
        *(ushort4*)(y + (size_t)m*1152 + c) = o4;
    }
}

// ---------------- GEMM (m97 structure): out = epi(A(bf16,MxK) @ Wt^T + bias) ----------------
// EPI: 0 = bf16 store, 1 = gelu->bf16, 2 = f32 store (guard row<M), 3 = x += gate*(v)
template<int EPI>
__global__ __launch_bounds__(256,2)
void gemm2_k(const unsigned short* __restrict__ A, int lda,
             const unsigned short* __restrict__ B, int ldb,
             const float* __restrict__ bias,
             unsigned short* __restrict__ outb, float* __restrict__ outf, int ldo,
             int M, int K,
             float* __restrict__ xres,
             const float* __restrict__ modb, int mld, int gofs){
    __shared__ unsigned short Alds[128*32];
    __shared__ unsigned short Blds[128*32];
    const int tid  = threadIdx.x;
    const int lane = tid & 63;
    const int wv   = tid >> 6;
    const int wr   = wv >> 1, wc = wv & 1;
    const int m0 = blockIdx.x * 128;
    const int n0 = blockIdx.y * 128;

    const int r0 = (wv*2 + 0)*16 + (lane >> 2);
    const int r1 = (wv*2 + 1)*16 + (lane >> 2);
    const unsigned short* ag0 = A + (size_t)(m0 + r0)*lda + (lane & 3)*8;
    const unsigned short* ag1 = A + (size_t)(m0 + r1)*lda + (lane & 3)*8;
    const unsigned short* bg0 = B + (size_t)(n0 + r0)*ldb + (lane & 3)*8;
    const unsigned short* bg1 = B + (size_t)(n0 + r1)*ldb + (lane & 3)*8;
    unsigned short* al0 = &Alds[(wv*2 + 0)*512];
    unsigned short* al1 = &Alds[(wv*2 + 1)*512];
    unsigned short* bl0 = &Blds[(wv*2 + 0)*512];
    unsigned short* bl1 = &Blds[(wv*2 + 1)*512];

    f32x4 acc[4][4];
    #pragma unroll
    for (int i = 0; i < 4; i++)
        #pragma unroll
        for (int j = 0; j < 4; j++){ f32x4 z = {0.f,0.f,0.f,0.f}; acc[i][j] = z; }

    for (int ks = 0; ks < K; ks += 32){
        if (ks) __syncthreads();
        gload_lds16((const void*)ag0, (void*)al0);
        gload_lds16((const void*)ag1, (void*)al1);
        gload_lds16((const void*)bg0, (void*)bl0);
        gload_lds16((const void*)bg1, (void*)bl1);
        ag0 += 32; ag1 += 32; bg0 += 32; bg1 += 32;
        __syncthreads();
        bf16x8 af[4], bfm[4];
        #pragma unroll
        for (int mt = 0; mt < 4; mt++)
            af[mt] = ldb8(&Alds[(wr*64 + mt*16 + (lane&15))*32 + (lane>>4)*8]);
        #pragma unroll
        for (int nt = 0; nt < 4; nt++)
            bfm[nt] = ldb8(&Blds[(wc*64 + nt*16 + (lane&15))*32 + (lane>>4)*8]);
        #pragma unroll
        for (int mt = 0; mt < 4; mt++)
            #pragma unroll
            for (int nt = 0; nt < 4; nt++)
                acc[mt][nt] = __builtin_amdgcn_mfma_f32_16x16x32_bf16(af[mt], bfm[nt], acc[mt][nt], 0,0,0);
    }

    const int cb = n0 + wc*64;
    const int rb = m0 + wr*64;
    #pragma unroll
    for (int nt = 0; nt < 4; nt++){
        int col = cb + nt*16 + (lane & 15);
        float bn = bias[col];
        #pragma unroll
        for (int mt = 0; mt < 4; mt++){
            #pragma unroll
            for (int i = 0; i < 4; i++){
                int row = rb + mt*16 + (lane>>4)*4 + i;
                float v = acc[mt][nt][i] + bn;
                if (EPI == 0){
                    outb[(size_t)row*ldo + col] = f2bf(v);
                } else if (EPI == 1){
                    float z = 0.7978845608f*(v + 0.044715f*v*v*v);
                    float e = __expf(-2.f*fabsf(z));
                    float th = (1.f - e)/(1.f + e);
                    th = (z >= 0.f) ? th : -th;
                    outb[(size_t)row*ldo + col] = f2bf(0.5f*v*(1.f + th));
                } else if (EPI == 2){
                    if (row < M) outf[(size_t)row*ldo + col] = v;
                } else {
                    int pos = row & 1023, bb2 = row >> 10;
                    int mrow = (pos < 512) ? pos : (512 + bb2);
                    float g = modb[(size_t)mrow*mld + gofs + col];
                    xres[(size_t)row*1152 + col] += g * v;
                }
            }
        }
    }
}

// ---------------- flash attention v3: 4 waves x 32 q rows, Q in regs, ones-col li ----------------
__global__ __launch_bounds__(256)
void attn3_k(const unsigned short* __restrict__ qkv, unsigned short* __restrict__ o){
    __shared__ unsigned short Kl[32*104];     // K tile, pitch 104 (pad cols 72..95 zero)
    __shared__ unsigned short Vt[80*40];      // V^T [d][kv], pitch 40; row 72 = ones (li trick)
    __shared__ unsigned short Pl[4][16*40];   // per-wave P
    const int tid  = threadIdx.x;
    const int lane = tid & 63;
    const int w    = tid >> 6;
    const int bid  = blockIdx.x;
    const int qb   = 7 - (bid >> 6);          // heavy blocks (qb=7: 32 tiles) first
    const int bh   = bid & 63;
    const int h = bh & 15, b = bh >> 4;
    const size_t base = (size_t)b*1024*3456;
    const int qcol = h*72, kcol = 1152 + h*72, vcol = 2304 + h*72;

    // one-time LDS init: K pad cols 72..95 zero; Vt rows 72..79 (ones row 72, zeros 73..79)
    for (int idx = tid; idx < 384; idx += 256){          // 32 rows x 12 words
        int r = idx/12, cw = idx - r*12;
        ((unsigned int*)Kl)[r*52 + 36 + cw] = 0u;
    }
    if (tid < 160){                                      // rows 72..79 x 20 words
        ((unsigned int*)Vt)[72*20 + tid] = (tid < 20) ? 0x3F803F80u : 0u;
    }

    // Q in registers: 2 m-tiles x 3 k-steps (k 0..95, cols >=72 zeroed)
    bf16x8 qreg[2][3];
    const int qrow0 = qb*128 + w*32;
    {
        bf16x8 z8 = {};
        #pragma unroll
        for (int m = 0; m < 2; m++){
            const unsigned short* qp = qkv + base + (size_t)(qrow0 + m*16 + (lane&15))*3456 + qcol;
            const int off = (lane>>4)*8;
            qreg[m][0] = ldb8(qp + off);
            qreg[m][1] = ldb8(qp + 32 + off);
            qreg[m][2] = (lane < 16) ? ldb8(qp + 64) : z8;   // cols 64..71 live in k-group 0
        }
    }

    float mi[2][4];
    f32x4 oa[2][5];
    #pragma unroll
    for (int m = 0; m < 2; m++){
        #pragma unroll
        for (int i = 0; i < 4; i++) mi[m][i] = -INFINITY;
        #pragma unroll
        for (int d = 0; d < 5; d++){ f32x4 z = {0.f,0.f,0.f,0.f}; oa[m][d] = z; }
    }

    const int ktmax = 4*qb + 4;
    const float qsc = 0.11785113019775793f;   // 72^-0.5

    for (int kt = 0; kt < ktmax; kt++){
        const int kvb = kt*32;
        __syncthreads();
        // stage K: 32 rows x 72 cols, ushort4 chunks
        for (int ch = tid; ch < 576; ch += 256){
            int r = ch/18, d4 = (ch - r*18)*4;
            *(ushort4*)&Kl[r*104 + d4] =
                *(const ushort4*)(qkv + base + (size_t)(kvb + r)*3456 + kcol + d4);
        }
        // stage V transposed: row-pair ushort2 writes (2-way banks = free)
        for (int ch = tid; ch < 288; ch += 256){
            int rp = ch & 15, d4 = (ch >> 4)*4;
            const unsigned short* vp = qkv + base + (size_t)(kvb + 2*rp)*3456 + vcol + d4;
            ushort4 v0 = *(const ushort4*)vp;
            ushort4 v1 = *(const ushort4*)(vp + 3456);
            *(ushort2*)&Vt[(d4+0)*40 + 2*rp] = make_ushort2(v0.x, v1.x);
            *(ushort2*)&Vt[(d4+1)*40 + 2*rp] = make_ushort2(v0.y, v1.y);
            *(ushort2*)&Vt[(d4+2)*40 + 2*rp] = make_ushort2(v0.z, v1.z);
            *(ushort2*)&Vt[(d4+3)*40 + 2*rp] = make_ushort2(v0.w, v1.w);
        }
        __syncthreads();

        #pragma unroll
        for (int m = 0; m < 2; m++){
            const int q0 = qrow0 + m*16;
            if (kvb > q0 + 15) continue;      // wave-uniform skip
            f32x4 s0 = {0.f,0.f,0.f,0.f}, s1 = {0.f,0.f,0.f,0.f};
            #pragma unroll
            for (int st = 0; st < 3; st++){
                bf16x8 k0 = ldb8(&Kl[(lane&15)*104 + (lane>>4)*8 + st*32]);
                bf16x8 k1 = ldb8(&Kl[(16+(lane&15))*104 + (lane>>4)*8 + st*32]);
                s0 = __builtin_amdgcn_mfma_f32_16x16x32_bf16(qreg[m][st], k0, s0, 0,0,0);
                s1 = __builtin_amdgcn_mfma_f32_16x16x32_bf16(qreg[m][st], k1, s1, 0,0,0);
            }
            const bool domask = (kvb + 31 > q0);
            float p0[4], p1[4];
            #pragma unroll
            for (int i = 0; i < 4; i++){
                float a = s0[i]*qsc, c = s1[i]*qsc;
                if (domask){
                    int r = q0 + (lane>>4)*4 + i;
                    if (kvb + (lane&15) > r) a = -1e30f;
                    if (kvb + 16 + (lane&15) > r) c = -1e30f;
                }
                float pm = fmaxf(a, c);
                #pragma unroll
                for (int off = 1; off < 16; off <<= 1) pm = fmaxf(pm, __shfl_xor(pm, off));
                float nm = fmaxf(mi[m][i], pm);
                float f = __expf(mi[m][i] - nm);
                mi[m][i] = nm;
                p0[i] = __expf(a - nm);
                p1[i] = __expf(c - nm);
                #pragma unroll
                for (int d = 0; d < 5; d++) oa[m][d][i] *= f;
            }
            unsigned short* Pw = Pl[w];
            #pragma unroll
            for (int i = 0; i < 4; i++){
                int r = (lane>>4)*4 + i;
                Pw[r*40 + (lane&15)]      = f2bf(p0[i]);
                Pw[r*40 + 16 + (lane&15)] = f2bf(p1[i]);
            }
            bf16x8 pa = ldb8(&Pw[(lane&15)*40 + (lane>>4)*8]);
            #pragma unroll
            for (int d = 0; d < 5; d++){
                bf16x8 bv = ldb8(&Vt[(d*16 + (lane&15))*40 + (lane>>4)*8]);
                oa[m][d] = __builtin_amdgcn_mfma_f32_16x16x32_bf16(pa, bv, oa[m][d], 0,0,0);
            }
        }
    }
    // epilogue: li lives at output-col 72 = frag d=4, col 8
    #pragma unroll
    for (int m = 0; m < 2; m++){
        const int q0 = qrow0 + m*16;
        #pragma unroll
        for (int i = 0; i < 4; i++){
            float li = __shfl(oa[m][4][i], (lane & 48) | 8);
            float inv = 1.f / li;
            size_t row = (size_t)b*1024 + q0 + (lane>>4)*4 + i;
            #pragma unroll
            for (int d = 0; d < 5; d++){
                int c = d*16 + (lane & 15);
                if (c < 72) o[row*1152 + h*72 + c] = f2bf(oa[m][d][i]*inv);
            }
        }
    }
}

// ---------------- final: out = modulate(x, sh, sc) @ fin_w + fin_b (GEN rows) ----------------
__global__ __launch_bounds__(256) void final_k(const float* __restrict__ x,
    const float* __restrict__ modf, const float* __restrict__ finw,
    const float* __restrict__ finb, float* __restrict__ outp){
    __shared__ float yl[1152];
    __shared__ float ps[8][32];
    const int t = threadIdx.x;
    for (int r = 0; r < 8; r++){
        int gr = blockIdx.x*8 + r;              // 0..2047 GEN rows
        int b = gr >> 9, p = gr & 511;
        size_t m = (size_t)b*1024 + 512 + p;
        int mrow = 512 + b;
        const float* xr = x + m*1152;
        const float* md = modf + (size_t)mrow*2304;
        for (int c = t; c < 1152; c += 256)
            yl[c] = xr[c]*(1.f + md[1152 + c]) + md[c];
        __syncthreads();
        int j = t & 31, g = t >> 5;
        float s = 0.f;
        for (int c = g*144; c < g*144 + 144; c++) s += yl[c]*finw[c*32 + j];
        ps[g][j] = s;
        __syncthreads();
        if (t < 32){
            float acc = finb[j];
            #pragma unroll
            for (int gg = 0; gg < 8; gg++) acc += ps[gg][j];
            outp[((size_t)b*512 + p)*32 + j] = acc;
        }
        __syncthreads();
    }
}

// ---------------- host launch ----------------
extern "C" void kernel_launch(void* const* d_in, const int* in_sizes, int n_in,
                              void* d_out, int out_size, void* d_ws, size_t ws_size,
                              hipStream_t stream){
    const float* xin   = (const float*)d_in[0];
    const float* noise = (const float*)d_in[1];
    const float* rawh  = (const float*)d_in[2];
    const float* pose  = (const float*)d_in[4];
    const float* plug  = (const float*)d_in[5];
    const float* t_w0  = (const float*)d_in[6];
    const float* t_b0  = (const float*)d_in[7];
    const float* t_w2  = (const float*)d_in[8];
    const float* t_b2  = (const float*)d_in[9];
    const float* qkvw  = (const float*)d_in[10];
    const float* qkvb  = (const float*)d_in[11];
    const float* projw = (const float*)d_in[12];
    const float* projb = (const float*)d_in[13];
    const float* fc1w  = (const float*)d_in[14];
    const float* fc1b  = (const float*)d_in[15];
    const float* fc2w  = (const float*)d_in[16];
    const float* fc2b  = (const float*)d_in[17];
    const float* adaw  = (const float*)d_in[18];
    const float* adab  = (const float*)d_in[19];
    const float* finaw = (const float*)d_in[20];
    const float* finab = (const float*)d_in[21];
    const float* finw  = (const float*)d_in[22];
    const float* finb  = (const float*)d_in[23];

    char* ws = (char*)d_ws;
    float*          xbuf  = (float*)(ws + 0);                      // 4096x1152 f32   (18.87 MB)
    unsigned short* ybuf  = (unsigned short*)(ws + 18874368);      // 4096x1152 bf16  (9.44 MB)
    unsigned short* qh    = (unsigned short*)(ws + 28311552);      // 4096x4608 bf16  (37.75 MB)
    unsigned short* siluc = (unsigned short*)(ws + 66060288);      // 640x1152 bf16   (1.47 MB)
    float*          modb  = (float*)(ws + 67534848);               // 516x6912 f32    (14.27 MB)
    unsigned short* wt    = (unsigned short*)(ws + 81801216);      // merged: 47.78 MB / fallback: 15.93 MB
    float*          hl    = (float*)qh;                            // 4x1152 f32, dead before qkv gemm

    const bool merged = (ws_size >= 129576960ul);

    silu_hist_k<<<2880,256,0,stream>>>(plug, siluc);
    cgen1_k<<<dim3(18,4),256,0,stream>>>(noise, t_w0, t_b0, hl);
    cgen2_k<<<dim3(18,4),256,0,stream>>>(hl, t_w2, t_b2, siluc);
    x0_k<<<4608,256,0,stream>>>(xin, rawh, pose, xbuf);

    // wt sub-offsets (bf16 elements) for merged layout
    unsigned short* wt_ada = wt;
    unsigned short* wt_qkv = merged ? wt +  7962624 : wt;
    unsigned short* wt_prj = merged ? wt + 11943936 : wt;
    unsigned short* wt_fc1 = merged ? wt + 13271040 : wt;
    unsigned short* wt_fc2 = merged ? wt + 18579456 : wt;

    for (int l = 0; l < 7; l++){
        if (merged){
            tw5_k<<<23328,256,0,stream>>>(adaw + (size_t)l*1152*6912, qkvw + (size_t)l*1152*3456,
                projw + (size_t)l*1152*1152, fc1w + (size_t)l*1152*4608,
                fc2w + (size_t)l*4608*1152, wt);
        } else {
            tw_k<<<dim3(216,36),256,0,stream>>>(adaw + (size_t)l*1152*6912, 1152, 6912, wt);
        }
        gemm2_k<2><<<dim3(5,54),256,0,stream>>>(siluc,1152, wt_ada,1152, adab + (size_t)l*6912,
            nullptr, modb, 6912, 516, 1152, nullptr, nullptr, 0, 0);
        ln_mod_k<<<4096,256,0,stream>>>(xbuf, modb, 6912, 0, ybuf);
        // qkv
        if (!merged) tw_k<<<dim3(108,36),256,0,stream>>>(qkvw + (size_t)l*1152*3456, 1152, 3456, wt);
        gemm2_k<0><<<dim3(32,27),256,0,stream>>>(ybuf,1152, wt_qkv,1152, qkvb + (size_t)l*3456,
            qh, nullptr, 3456, 4096, 1152, nullptr, nullptr, 0, 0);
        attn3_k<<<512,256,0,stream>>>(qh, ybuf);
        // proj (+ gated residual into xbuf)
        if (!merged) tw_k<<<dim3(36,36),256,0,stream>>>(projw + (size_t)l*1152*1152, 1152, 1152, wt);
        gemm2_k<3><<<dim3(32,9),256,0,stream>>>(ybuf,1152, wt_prj,1152, projb + (size_t)l*1152,
            nullptr, nullptr, 1152, 4096, 1152, xbuf, modb, 6912, 2304);
        ln_mod_k<<<4096,256,0,stream>>>(xbuf, modb, 6912, 3456, ybuf);
        // fc1 (gelu)
        if (!merged) tw_k<<<dim3(144,36),256,0,stream>>>(fc1w + (size_t)l*1152*4608, 1152, 4608, wt);
        gemm2_k<1><<<dim3(32,36),256,0,stream>>>(ybuf,1152, wt_fc1,1152, fc1b + (size_t)l*4608,
            qh, nullptr, 4608, 4096, 1152, nullptr, nullptr, 0, 0);
        // fc2 (+ gated residual into xbuf)
        if (!merged) tw_k<<<dim3(36,144),256,0,stream>>>(fc2w + (size_t)l*4608*1152, 4608, 1152, wt);
        gemm2_k<3><<<dim3(32,9),256,0,stream>>>(qh,4608, wt_fc2,4608, fc2b + (size_t)l*1152,
            nullptr, nullptr, 1152, 4096, 4608, xbuf, modb, 6912, 5760);
    }
    // final adaLN + projection
    tw_k<<<dim3(72,36),256,0,stream>>>(finaw, 1152, 2304, wt);
    gemm2_k<2><<<dim3(5,18),256,0,stream>>>(siluc,1152, wt,1152, finab,
        nullptr, modb, 2304, 516, 1152, nullptr, nullptr, 0, 0);
    final_k<<<256,256,0,stream>>>(xbuf, modb, finw, finb, (float*)d_out);
}

// Round 6
// 2938.386 us; speedup vs baseline: 1.9738x; 1.1308x over previous
//
#include <hip/hip_runtime.h>

// ---------------- types & helpers ----------------
typedef float f32x4 __attribute__((ext_vector_type(4)));
typedef __bf16 bf16x8 __attribute__((ext_vector_type(8)));
typedef unsigned short us8 __attribute__((ext_vector_type(8)));

static __device__ __forceinline__ unsigned short f2bf(float f){
    unsigned int u = __builtin_bit_cast(unsigned int, f);
    u += 0x7fffu + ((u >> 16) & 1u);
    return (unsigned short)(u >> 16);
}
static __device__ __forceinline__ bf16x8 ldb8(const unsigned short* p){
    return __builtin_bit_cast(bf16x8, *(const us8*)p);
}
typedef __attribute__((address_space(1))) void gas_void;
typedef __attribute__((address_space(3))) void las_void;
static __device__ __forceinline__ void gload_lds16(const void* g, void* l){
    __builtin_amdgcn_global_load_lds((gas_void*)g, (las_void*)l, 16, 0, 0);
}
static __device__ __forceinline__ float siluf(float v){
    return v / (1.f + __expf(-v));
}

// ---------------- prep: silu(plug_c_ref) rows 0..511, zero pad rows 512..639 ----------------
__global__ __launch_bounds__(256) void silu_hist_k(const float* __restrict__ plug,
                                                   unsigned short* __restrict__ siluc){
    int i = blockIdx.x*256 + threadIdx.x;
    if (i < 512*1152){
        siluc[i] = f2bf(siluf(plug[i]));
    } else if (i < 640*1152){
        siluc[i] = 0;   // pad rows: safe A-tile overread for M=516 GEMMs
    }
}

// ---------------- timestep MLP stage 1 (split-K x4): hl = silu(emb @ t_w0 + b0) ----------------
__global__ __launch_bounds__(256) void cgen1_k(const float* __restrict__ noise,
    const float* __restrict__ t_w0, const float* __restrict__ t_b0,
    float* __restrict__ hl){
    __shared__ float emb[256];
    __shared__ float part[4][64];
    const int t = threadIdx.x;
    const int b = blockIdx.y;
    const int c = blockIdx.x*64 + (t & 63);
    const int kg = t >> 6;
    const float tv = noise[b];
    if (t < 128){
        float arg = tv * __expf(-0.07195578415606394f * (float)t);
        emb[t] = cosf(arg);
        emb[128 + t] = sinf(arg);
    }
    __syncthreads();
    float s = 0.f;
    #pragma unroll 4
    for (int j = kg*64; j < kg*64 + 64; j++) s += emb[j] * t_w0[j*1152 + c];
    part[kg][t & 63] = s;
    __syncthreads();
    if (t < 64){
        float v = part[0][t] + part[1][t] + part[2][t] + part[3][t] + t_b0[c];
        hl[b*1152 + c] = siluf(v);
    }
}

// ---------------- timestep MLP stage 2 (split-K x4): siluc[512+b] = silu(hl @ t_w2 + b2) ----------------
__global__ __launch_bounds__(256) void cgen2_k(const float* __restrict__ hl,
    const float* __restrict__ t_w2, const float* __restrict__ t_b2,
    unsigned short* __restrict__ siluc){
    __shared__ float h[1152];
    __shared__ float part[4][64];
    const int t = threadIdx.x;
    const int b = blockIdx.y;
    const int c = blockIdx.x*64 + (t & 63);
    const int kg = t >> 6;
    for (int j = t; j < 1152; j += 256) h[j] = hl[b*1152 + j];
    __syncthreads();
    float s = 0.f;
    #pragma unroll 4
    for (int j = kg*288; j < kg*288 + 288; j++) s += h[j] * t_w2[j*1152 + c];
    part[kg][t & 63] = s;
    __syncthreads();
    if (t < 64){
        float v = part[0][t] + part[1][t] + part[2][t] + part[3][t] + t_b2[c];
        siluc[(size_t)(512 + b)*1152 + c] = f2bf(siluf(v));
    }
}

// ---------------- prep: x0 = tile(concat(rawhist,x),36) + pos_embed ----------------
__global__ __launch_bounds__(256) void x0_k(const float* __restrict__ xg,
    const float* __restrict__ rh, const float* __restrict__ pe, float* __restrict__ x){
    int i4 = blockIdx.x*256 + threadIdx.x;          // float4 index
    if (i4 >= 1179648) return;                      // 4096*1152/4
    int m = i4 / 288;
    int c = (i4 - m*288) * 4;
    int pos = m & 1023, b = m >> 10;
    const float* src = (pos < 512) ? (rh + ((size_t)b*512 + pos)*32)
                                   : (xg + ((size_t)b*512 + (pos-512))*32);
    float4 sv = *(const float4*)(src + (c & 31));
    float4 pv = *(const float4*)(pe + (size_t)pos*1152 + c);
    float4 o; o.x = sv.x+pv.x; o.y = sv.y+pv.y; o.z = sv.z+pv.z; o.w = sv.w+pv.w;
    *(float4*)(x + (size_t)i4*4) = o;
}

// ---------------- weight transpose-convert: W f32 [K][N] -> Wt bf16 [N][K] ----------------
__global__ __launch_bounds__(256) void tw_k(const float* __restrict__ W, int Kd, int Nd,
                                            unsigned short* __restrict__ Wt){
    __shared__ float tile[32][33];
    int n0 = blockIdx.x*32, k0 = blockIdx.y*32;
    int t = threadIdx.x;
    #pragma unroll
    for (int i = 0; i < 4; i++){
        int idx = t + 256*i;
        int kk = idx >> 5, nn = idx & 31;
        tile[kk][nn] = W[(size_t)(k0+kk)*Nd + n0+nn];
    }
    __syncthreads();
    #pragma unroll
    for (int i = 0; i < 4; i++){
        int idx = t + 256*i;
        int nn = idx >> 5, kk = idx & 31;
        Wt[(size_t)(n0+nn)*Kd + k0+kk] = f2bf(tile[kk][nn]);
    }
}

// ---------------- merged per-layer transpose: all 5 weights in one launch ----------------
// tiles: ada 216x36=7776 | qkv 108x36=3888 | proj 36x36=1296 | fc1 144x36=5184 | fc2 36x144=5184
__global__ __launch_bounds__(256) void tw5_k(const float* __restrict__ w0,
    const float* __restrict__ w1, const float* __restrict__ w2,
    const float* __restrict__ w3, const float* __restrict__ w4,
    unsigned short* __restrict__ wt){
    __shared__ float tile[32][33];
    const int cum[5]  = {7776, 11664, 12960, 18144, 23328};
    const int kds[5]  = {1152, 1152, 1152, 1152, 4608};
    const int nds[5]  = {6912, 3456, 1152, 4608, 1152};
    const size_t dof[5] = {0ul, 7962624ul, 11943936ul, 13271040ul, 18579456ul};
    int bid = blockIdx.x;
    int w = (bid < cum[1]) ? ((bid < cum[0]) ? 0 : 1)
                           : ((bid < cum[2]) ? 2 : (bid < cum[3]) ? 3 : 4);
    int local = bid - (w ? cum[w-1] : 0);
    const float* W = (w==0)?w0:(w==1)?w1:(w==2)?w2:(w==3)?w3:w4;
    unsigned short* Wt = wt + dof[w];
    const int Kd = kds[w], Nd = nds[w];
    const int ntx = Nd >> 5;
    const int n0 = (local % ntx)*32, k0 = (local / ntx)*32;
    const int t = threadIdx.x;
    #pragma unroll
    for (int i = 0; i < 4; i++){
        int idx = t + 256*i;
        int kk = idx >> 5, nn = idx & 31;
        tile[kk][nn] = W[(size_t)(k0+kk)*Nd + n0+nn];
    }
    __syncthreads();
    #pragma unroll
    for (int i = 0; i < 4; i++){
        int idx = t + 256*i;
        int nn = idx >> 5, kk = idx & 31;
        Wt[(size_t)(n0+nn)*Kd + k0+kk] = f2bf(tile[kk][nn]);
    }
}

// ---------------- LN (no affine) + modulate -> bf16 ----------------
__global__ __launch_bounds__(256) void ln_mod_k(const float* __restrict__ x,
    const float* __restrict__ modb, int mld, int ofs, unsigned short* __restrict__ y){
    const int m = blockIdx.x, t = threadIdx.x;
    const int lane = t & 63, wv = t >> 6;
    const float* xr = x + (size_t)m*1152;
    float4 v0 = ((const float4*)xr)[t];
    float4 v1 = {0.f,0.f,0.f,0.f};
    bool h2 = (t < 32);
    if (h2) v1 = ((const float4*)xr)[256 + t];
    float s = v0.x+v0.y+v0.z+v0.w + v1.x+v1.y+v1.z+v1.w;
    float q = v0.x*v0.x+v0.y*v0.y+v0.z*v0.z+v0.w*v0.w
            + v1.x*v1.x+v1.y*v1.y+v1.z*v1.z+v1.w*v1.w;
    #pragma unroll
    for (int o = 32; o; o >>= 1){ s += __shfl_xor(s,o); q += __shfl_xor(q,o); }
    __shared__ float red[8];
    if (lane == 0){ red[wv] = s; red[4+wv] = q; }
    __syncthreads();
    s = red[0]+red[1]+red[2]+red[3];
    q = red[4]+red[5]+red[6]+red[7];
    const float mean = s * (1.f/1152.f);
    const float var  = q * (1.f/1152.f) - mean*mean;
    const float rstd = rsqrtf(var + 1e-6f);
    const int pos = m & 1023, bb = m >> 10;
    const int mrow = (pos < 512) ? pos : (512 + bb);
    const float* sh = modb + (size_t)mrow*mld + ofs;
    const float* sc = sh + 1152;
    {
        int c = t*4;
        float4 shv = *(const float4*)(sh + c);
        float4 scv = *(const float4*)(sc + c);
        ushort4 o4;
        o4.x = f2bf((v0.x-mean)*rstd*(1.f+scv.x) + shv.x);
        o4.y = f2bf((v0.y-mean)*rstd*(1.f+scv.y) + shv.y);
        o4.z = f2bf((v0.z-mean)*rstd*(1.f+scv.z) + shv.z);
        o4.w = f2bf((v0.w-mean)*rstd*(1.f+scv.w) + shv.w);
        *(ushort4*)(y + (size_t)m*1152 + c) = o4;
    }
    if (h2){
        int c = 1024 + t*4;
        float4 shv = *(const float4*)(sh + c);
        float4 scv = *(const float4*)(sc + c);
        ushort4 o4;
        o4.x = f2bf((v1.x-mean)*rstd*(1.f+scv.x) + shv.x);
        o4.y = f2bf((v1.y-mean)*rstd*(1.f+scv.y) + shv.y);
        o4.z = f2bf((v1.z-mean)*rstd*(1.f+scv.z) + shv.z);
        o4.w = f2bf((v1.w-mean)*rstd*(1.f+scv.w) + shv.w);
        *(ushort4*)(y + (size_t)m*1152 + c) = o4;
    }
}

// ---------------- GEMM (m97 structure): out = epi(A(bf16,MxK) @ Wt^T + bias) ----------------
// EPI: 0 = bf16 store, 1 = gelu->bf16, 2 = f32 store (guard row<M), 3 = x += gate*(v)
template<int EPI>
__global__ __launch_bounds__(256,2)
void gemm2_k(const unsigned short* __restrict__ A, int lda,
             const unsigned short* __restrict__ B, int ldb,
             const float* __restrict__ bias,
             unsigned short* __restrict__ outb, float* __restrict__ outf, int ldo,
             int M, int K,
             float* __restrict__ xres,
             const float* __restrict__ modb, int mld, int gofs){
    __shared__ unsigned short Alds[128*32];
    __shared__ unsigned short Blds[128*32];
    const int tid  = threadIdx.x;
    const int lane = tid & 63;
    const int wv   = tid >> 6;
    const int wr   = wv >> 1, wc = wv & 1;
    const int m0 = blockIdx.x * 128;
    const int n0 = blockIdx.y * 128;

    const int r0 = (wv*2 + 0)*16 + (lane >> 2);
    const int r1 = (wv*2 + 1)*16 + (lane >> 2);
    const unsigned short* ag0 = A + (size_t)(m0 + r0)*lda + (lane & 3)*8;
    const unsigned short* ag1 = A + (size_t)(m0 + r1)*lda + (lane & 3)*8;
    const unsigned short* bg0 = B + (size_t)(n0 + r0)*ldb + (lane & 3)*8;
    const unsigned short* bg1 = B + (size_t)(n0 + r1)*ldb + (lane & 3)*8;
    unsigned short* al0 = &Alds[(wv*2 + 0)*512];
    unsigned short* al1 = &Alds[(wv*2 + 1)*512];
    unsigned short* bl0 = &Blds[(wv*2 + 0)*512];
    unsigned short* bl1 = &Blds[(wv*2 + 1)*512];

    f32x4 acc[4][4];
    #pragma unroll
    for (int i = 0; i < 4; i++)
        #pragma unroll
        for (int j = 0; j < 4; j++){ f32x4 z = {0.f,0.f,0.f,0.f}; acc[i][j] = z; }

    for (int ks = 0; ks < K; ks += 32){
        if (ks) __syncthreads();
        gload_lds16((const void*)ag0, (void*)al0);
        gload_lds16((const void*)ag1, (void*)al1);
        gload_lds16((const void*)bg0, (void*)bl0);
        gload_lds16((const void*)bg1, (void*)bl1);
        ag0 += 32; ag1 += 32; bg0 += 32; bg1 += 32;
        __syncthreads();
        bf16x8 af[4], bfm[4];
        #pragma unroll
        for (int mt = 0; mt < 4; mt++)
            af[mt] = ldb8(&Alds[(wr*64 + mt*16 + (lane&15))*32 + (lane>>4)*8]);
        #pragma unroll
        for (int nt = 0; nt < 4; nt++)
            bfm[nt] = ldb8(&Blds[(wc*64 + nt*16 + (lane&15))*32 + (lane>>4)*8]);
        #pragma unroll
        for (int mt = 0; mt < 4; mt++)
            #pragma unroll
            for (int nt = 0; nt < 4; nt++)
                acc[mt][nt] = __builtin_amdgcn_mfma_f32_16x16x32_bf16(af[mt], bfm[nt], acc[mt][nt], 0,0,0);
    }

    const int cb = n0 + wc*64;
    const int rb = m0 + wr*64;
    #pragma unroll
    for (int nt = 0; nt < 4; nt++){
        int col = cb + nt*16 + (lane & 15);
        float bn = bias[col];
        #pragma unroll
        for (int mt = 0; mt < 4; mt++){
            #pragma unroll
            for (int i = 0; i < 4; i++){
                int row = rb + mt*16 + (lane>>4)*4 + i;
                float v = acc[mt][nt][i] + bn;
                if (EPI == 0){
                    outb[(size_t)row*ldo + col] = f2bf(v);
                } else if (EPI == 1){
                    float z = 0.7978845608f*(v + 0.044715f*v*v*v);
                    float e = __expf(-2.f*fabsf(z));
                    float th = (1.f - e)/(1.f + e);
                    th = (z >= 0.f) ? th : -th;
                    outb[(size_t)row*ldo + col] = f2bf(0.5f*v*(1.f + th));
                } else if (EPI == 2){
                    if (row < M) outf[(size_t)row*ldo + col] = v;
                } else {
                    int pos = row & 1023, bb2 = row >> 10;
                    int mrow = (pos < 512) ? pos : (512 + bb2);
                    float g = modb[(size_t)mrow*mld + gofs + col];
                    xres[(size_t)row*1152 + col] += g * v;
                }
            }
        }
    }
}

// ---------------- flash attention v5: 8 waves x 16 q rows, 128-kv super-tiles ----------------
// Block = (b, h, qb of 128 q-rows). K[128][104], Vt[80][136] staged once per super-tile;
// 4 kv-subtiles of compute between one barrier pair. Q in regs; ones-row li trick.
__global__ __launch_bounds__(512)
void attn5_k(const unsigned short* __restrict__ qkv, unsigned short* __restrict__ o){
    __shared__ unsigned short Kl[128*104];    // 26.0 KB
    __shared__ unsigned short Vt[80*136];     // 21.25 KB  [d][kv], row 72 = ones
    __shared__ unsigned short Pl[8][16*40];   // 10 KB
    const int tid  = threadIdx.x;
    const int lane = tid & 63;
    const int w    = tid >> 6;
    const int bid  = blockIdx.x;
    const int qb   = 7 - (bid >> 6);          // heavy blocks first
    const int bh   = bid & 63;
    const int h = bh & 15, b = bh >> 4;
    const size_t base = (size_t)b*1024*3456;
    const int qcol = h*72, kcol = 1152 + h*72, vcol = 2304 + h*72;

    // one-time LDS init: K pad cols 72..103 (16 words x 128 rows); Vt rows 72..79
    for (int idx = tid; idx < 2048; idx += 512){
        int r = idx >> 4, cw = idx & 15;
        ((unsigned int*)Kl)[r*52 + 36 + cw] = 0u;
    }
    if (tid < 544){                            // 8 rows x 68 words
        int r = tid/68;
        ((unsigned int*)Vt)[(72+r)*68 + (tid - r*68)] = (r == 0) ? 0x3F803F80u : 0u;
    }

    // Q in registers: 16 rows per wave
    bf16x8 qreg[3];
    const int q0 = qb*128 + w*16;
    {
        bf16x8 z8 = {};
        const unsigned short* qp = qkv + base + (size_t)(q0 + (lane&15))*3456 + qcol;
        const int off = (lane>>4)*8;
        qreg[0] = ldb8(qp + off);
        qreg[1] = ldb8(qp + 32 + off);
        qreg[2] = (lane < 16) ? ldb8(qp + 64) : z8;   // cols 64..71 in k-group 0; 72..95 zero
    }

    float mi[4];
    f32x4 oa[5];
    #pragma unroll
    for (int i = 0; i < 4; i++) mi[i] = -INFINITY;
    #pragma unroll
    for (int d = 0; d < 5; d++){ f32x4 z = {0.f,0.f,0.f,0.f}; oa[d] = z; }

    const int nS = qb + 1;
    const float qsc = 0.11785113019775793f;   // 72^-0.5

    for (int S = 0; S < nS; S++){
        const int kvS = S*128;
        __syncthreads();
        // stage K: 128 rows x 72 cols (ushort4)
        for (int ch = tid; ch < 2304; ch += 512){
            int r = ch/18, d4 = (ch - r*18)*4;
            *(ushort4*)&Kl[r*104 + d4] =
                *(const ushort4*)(qkv + base + (size_t)(kvS + r)*3456 + kcol + d4);
        }
        // stage V transposed: row-pair ushort2 writes (2-way banks = free)
        for (int ch = tid; ch < 1152; ch += 512){
            int rp = ch & 63, d4 = (ch >> 6)*4;
            const unsigned short* vp = qkv + base + (size_t)(kvS + 2*rp)*3456 + vcol + d4;
            ushort4 v0 = *(const ushort4*)vp;
            ushort4 v1 = *(const ushort4*)(vp + 3456);
            *(ushort2*)&Vt[(d4+0)*136 + 2*rp] = make_ushort2(v0.x, v1.x);
            *(ushort2*)&Vt[(d4+1)*136 + 2*rp] = make_ushort2(v0.y, v1.y);
            *(ushort2*)&Vt[(d4+2)*136 + 2*rp] = make_ushort2(v0.z, v1.z);
            *(ushort2*)&Vt[(d4+3)*136 + 2*rp] = make_ushort2(v0.w, v1.w);
        }
        __syncthreads();

        for (int sub = 0; sub < 4; sub++){
            const int kvb = kvS + sub*32;
            if (kvb > q0 + 15) break;         // wave-uniform
            f32x4 s0 = {0.f,0.f,0.f,0.f}, s1 = {0.f,0.f,0.f,0.f};
            __builtin_amdgcn_s_setprio(1);
            #pragma unroll
            for (int st = 0; st < 3; st++){
                bf16x8 k0 = ldb8(&Kl[(sub*32 + (lane&15))*104 + (lane>>4)*8 + st*32]);
                bf16x8 k1 = ldb8(&Kl[(sub*32 + 16 + (lane&15))*104 + (lane>>4)*8 + st*32]);
                s0 = __builtin_amdgcn_mfma_f32_16x16x32_bf16(qreg[st], k0, s0, 0,0,0);
                s1 = __builtin_amdgcn_mfma_f32_16x16x32_bf16(qreg[st], k1, s1, 0,0,0);
            }
            __builtin_amdgcn_s_setprio(0);
            const bool domask = (kvb + 31 > q0);
            float p0[4], p1[4];
            #pragma unroll
            for (int i = 0; i < 4; i++){
                float a = s0[i]*qsc, c = s1[i]*qsc;
                if (domask){
                    int r = q0 + (lane>>4)*4 + i;
                    if (kvb + (lane&15) > r) a = -1e30f;
                    if (kvb + 16 + (lane&15) > r) c = -1e30f;
                }
                float pm = fmaxf(a, c);
                #pragma unroll
                for (int off = 1; off < 16; off <<= 1) pm = fmaxf(pm, __shfl_xor(pm, off));
                float nm = fmaxf(mi[i], pm);
                float f = __expf(mi[i] - nm);
                mi[i] = nm;
                p0[i] = __expf(a - nm);
                p1[i] = __expf(c - nm);
                #pragma unroll
                for (int d = 0; d < 5; d++) oa[d][i] *= f;
            }
            unsigned short* Pw = Pl[w];
            #pragma unroll
            for (int i = 0; i < 4; i++){
                int r = (lane>>4)*4 + i;
                Pw[r*40 + (lane&15)]      = f2bf(p0[i]);
                Pw[r*40 + 16 + (lane&15)] = f2bf(p1[i]);
            }
            bf16x8 pa = ldb8(&Pw[(lane&15)*40 + (lane>>4)*8]);
            __builtin_amdgcn_s_setprio(1);
            #pragma unroll
            for (int d = 0; d < 5; d++){
                bf16x8 bv = ldb8(&Vt[(d*16 + (lane&15))*136 + sub*32 + (lane>>4)*8]);
                oa[d] = __builtin_amdgcn_mfma_f32_16x16x32_bf16(pa, bv, oa[d], 0,0,0);
            }
            __builtin_amdgcn_s_setprio(0);
        }
    }
    // epilogue: li lives at output-col 72 = frag d=4, col 8
    #pragma unroll
    for (int i = 0; i < 4; i++){
        float li = __shfl(oa[4][i], (lane & 48) | 8);
        float inv = 1.f / li;
        size_t row = (size_t)b*1024 + q0 + (lane>>4)*4 + i;
        #pragma unroll
        for (int d = 0; d < 5; d++){
            int c = d*16 + (lane & 15);
            if (c < 72) o[row*1152 + h*72 + c] = f2bf(oa[d][i]*inv);
        }
    }
}

// ---------------- final: out = modulate(x, sh, sc) @ fin_w + fin_b (GEN rows) ----------------
__global__ __launch_bounds__(256) void final_k(const float* __restrict__ x,
    const float* __restrict__ modf, const float* __restrict__ finw,
    const float* __restrict__ finb, float* __restrict__ outp){
    __shared__ float yl[1152];
    __shared__ float ps[8][32];
    const int t = threadIdx.x;
    for (int r = 0; r < 8; r++){
        int gr = blockIdx.x*8 + r;              // 0..2047 GEN rows
        int b = gr >> 9, p = gr & 511;
        size_t m = (size_t)b*1024 + 512 + p;
        int mrow = 512 + b;
        const float* xr = x + m*1152;
        const float* md = modf + (size_t)mrow*2304;
        for (int c = t; c < 1152; c += 256)
            yl[c] = xr[c]*(1.f + md[1152 + c]) + md[c];
        __syncthreads();
        int j = t & 31, g = t >> 5;
        float s = 0.f;
        for (int c = g*144; c < g*144 + 144; c++) s += yl[c]*finw[c*32 + j];
        ps[g][j] = s;
        __syncthreads();
        if (t < 32){
            float acc = finb[j];
            #pragma unroll
            for (int gg = 0; gg < 8; gg++) acc += ps[gg][j];
            outp[((size_t)b*512 + p)*32 + j] = acc;
        }
        __syncthreads();
    }
}

// ---------------- host launch ----------------
extern "C" void kernel_launch(void* const* d_in, const int* in_sizes, int n_in,
                              void* d_out, int out_size, void* d_ws, size_t ws_size,
                              hipStream_t stream){
    const float* xin   = (const float*)d_in[0];
    const float* noise = (const float*)d_in[1];
    const float* rawh  = (const float*)d_in[2];
    const float* pose  = (const float*)d_in[4];
    const float* plug  = (const float*)d_in[5];
    const float* t_w0  = (const float*)d_in[6];
    const float* t_b0  = (const float*)d_in[7];
    const float* t_w2  = (const float*)d_in[8];
    const float* t_b2  = (const float*)d_in[9];
    const float* qkvw  = (const float*)d_in[10];
    const float* qkvb  = (const float*)d_in[11];
    const float* projw = (const float*)d_in[12];
    const float* projb = (const float*)d_in[13];
    const float* fc1w  = (const float*)d_in[14];
    const float* fc1b  = (const float*)d_in[15];
    const float* fc2w  = (const float*)d_in[16];
    const float* fc2b  = (const float*)d_in[17];
    const float* adaw  = (const float*)d_in[18];
    const float* adab  = (const float*)d_in[19];
    const float* finaw = (const float*)d_in[20];
    const float* finab = (const float*)d_in[21];
    const float* finw  = (const float*)d_in[22];
    const float* finb  = (const float*)d_in[23];

    char* ws = (char*)d_ws;
    float*          xbuf  = (float*)(ws + 0);                      // 4096x1152 f32   (18.87 MB)
    unsigned short* ybuf  = (unsigned short*)(ws + 18874368);      // 4096x1152 bf16  (9.44 MB)
    unsigned short* qh    = (unsigned short*)(ws + 28311552);      // 4096x4608 bf16  (37.75 MB)
    unsigned short* siluc = (unsigned short*)(ws + 66060288);      // 640x1152 bf16   (1.47 MB)
    float*          modb  = (float*)(ws + 67534848);               // 516x6912 f32    (14.27 MB)
    unsigned short* wt    = (unsigned short*)(ws + 81801216);      // merged: 47.78 MB / fallback: 15.93 MB
    float*          hl    = (float*)qh;                            // 4x1152 f32, dead before qkv gemm

    const bool merged = (ws_size >= 129576960ul);

    silu_hist_k<<<2880,256,0,stream>>>(plug, siluc);
    cgen1_k<<<dim3(18,4),256,0,stream>>>(noise, t_w0, t_b0, hl);
    cgen2_k<<<dim3(18,4),256,0,stream>>>(hl, t_w2, t_b2, siluc);
    x0_k<<<4608,256,0,stream>>>(xin, rawh, pose, xbuf);

    // wt sub-offsets (bf16 elements) for merged layout
    unsigned short* wt_ada = wt;
    unsigned short* wt_qkv = merged ? wt +  7962624 : wt;
    unsigned short* wt_prj = merged ? wt + 11943936 : wt;
    unsigned short* wt_fc1 = merged ? wt + 13271040 : wt;
    unsigned short* wt_fc2 = merged ? wt + 18579456 : wt;

    for (int l = 0; l < 7; l++){
        if (merged){
            tw5_k<<<23328,256,0,stream>>>(adaw + (size_t)l*1152*6912, qkvw + (size_t)l*1152*3456,
                projw + (size_t)l*1152*1152, fc1w + (size_t)l*1152*4608,
                fc2w + (size_t)l*4608*1152, wt);
        } else {
            tw_k<<<dim3(216,36),256,0,stream>>>(adaw + (size_t)l*1152*6912, 1152, 6912, wt);
        }
        gemm2_k<2><<<dim3(5,54),256,0,stream>>>(siluc,1152, wt_ada,1152, adab + (size_t)l*6912,
            nullptr, modb, 6912, 516, 1152, nullptr, nullptr, 0, 0);
        ln_mod_k<<<4096,256,0,stream>>>(xbuf, modb, 6912, 0, ybuf);
        // qkv
        if (!merged) tw_k<<<dim3(108,36),256,0,stream>>>(qkvw + (size_t)l*1152*3456, 1152, 3456, wt);
        gemm2_k<0><<<dim3(32,27),256,0,stream>>>(ybuf,1152, wt_qkv,1152, qkvb + (size_t)l*3456,
            qh, nullptr, 3456, 4096, 1152, nullptr, nullptr, 0, 0);
        attn5_k<<<512,512,0,stream>>>(qh, ybuf);
        // proj (+ gated residual into xbuf)
        if (!merged) tw_k<<<dim3(36,36),256,0,stream>>>(projw + (size_t)l*1152*1152, 1152, 1152, wt);
        gemm2_k<3><<<dim3(32,9),256,0,stream>>>(ybuf,1152, wt_prj,1152, projb + (size_t)l*1152,
            nullptr, nullptr, 1152, 4096, 1152, xbuf, modb, 6912, 2304);
        ln_mod_k<<<4096,256,0,stream>>>(xbuf, modb, 6912, 3456, ybuf);
        // fc1 (gelu)
        if (!merged) tw_k<<<dim3(144,36),256,0,stream>>>(fc1w + (size_t)l*1152*4608, 1152, 4608, wt);
        gemm2_k<1><<<dim3(32,36),256,0,stream>>>(ybuf,1152, wt_fc1,1152, fc1b + (size_t)l*4608,
            qh, nullptr, 4608, 4096, 1152, nullptr, nullptr, 0, 0);
        // fc2 (+ gated residual into xbuf)
        if (!merged) tw_k<<<dim3(36,144),256,0,stream>>>(fc2w + (size_t)l*4608*1152, 4608, 1152, wt);
        gemm2_k<3><<<dim3(32,9),256,0,stream>>>(qh,4608, wt_fc2,4608, fc2b + (size_t)l*1152,
            nullptr, nullptr, 1152, 4096, 4608, xbuf, modb, 6912, 5760);
    }
    // final adaLN + projection
    tw_k<<<dim3(72,36),256,0,stream>>>(finaw, 1152, 2304, wt);
    gemm2_k<2><<<dim3(5,18),256,0,stream>>>(siluc,1152, wt,1152, finab,
        nullptr, modb, 2304, 516, 1152, nullptr, nullptr, 0, 0);
    final_k<<<256,256,0,stream>>>(xbuf, modb, finw, finb, (float*)d_out);
}